// Round 9
// baseline (454.046 us; speedup 1.0000x reference)
//
#include <hip/hip_runtime.h>
#include <hip/hip_bf16.h>
#include <math.h>

#define B_ 128
#define L_ 50
#define D_ 128
#define S_ 12
#define NEG_INF_ -9e15f

typedef __attribute__((ext_vector_type(8))) _Float16 half8;
typedef __attribute__((ext_vector_type(4))) float f32x4;

static __device__ __forceinline__ float4 ld4(const float* p){ return *(const float4*)p; }
static __device__ __forceinline__ float lrelu(float x){ return fmaxf(x, 0.2f*x); }

// ---------------------------------------------------------------------------
// Local aggregator: 4-edge-type GAT. Grid (B, 4).
// ---------------------------------------------------------------------------
__global__ __launch_bounds__(256) void local_agg_kernel(
    const int* __restrict__ inputs, const int* __restrict__ adj,
    const float* __restrict__ emb,
    const float* __restrict__ a0, const float* __restrict__ a1,
    const float* __restrict__ a2, const float* __restrict__ a3,
    float* __restrict__ hlocal_out)
{
  __shared__ float hs[L_][129];
  __shared__ float alds[4][129];
  __shared__ float att[13][51];
  const int b = blockIdx.x, tid = threadIdx.x;
  const int r0 = blockIdx.y * 13;
  const int nr = (L_ - r0) < 13 ? (L_ - r0) : 13;

  if (tid < 128){
    alds[0][tid] = a0[tid]; alds[1][tid] = a1[tid];
    alds[2][tid] = a2[tid]; alds[3][tid] = a3[tid];
  }
  for (int i = tid; i < L_*D_; i += 256){
    int r = i >> 7, d = i & 127;
    hs[r][d] = emb[(size_t)inputs[b*L_ + r]*D_ + d];
  }
  __syncthreads();

  for (int pth = tid; pth < nr*L_; pth += 256){
    int i = pth / L_, j = pth % L_;
    int at = adj[b*L_*L_ + (r0+i)*L_ + j];
    float lg = NEG_INF_;
    if (at >= 1 && at <= 4){
      const float* av = alds[at-1];
      float acc = 0.f;
      #pragma unroll 4
      for (int d = 0; d < D_; ++d) acc = fmaf(hs[r0+i][d]*hs[j][d], av[d], acc);
      lg = lrelu(acc);
    }
    att[i][j] = lg;
  }
  __syncthreads();

  if (tid < nr){
    float m = -1e30f;
    for (int j = 0; j < L_; ++j) m = fmaxf(m, att[tid][j]);
    float sum = 0.f;
    for (int j = 0; j < L_; ++j){ float e = expf(att[tid][j]-m); att[tid][j] = e; sum += e; }
    float inv = 1.f/sum;
    for (int j = 0; j < L_; ++j) att[tid][j] *= inv;
  }
  __syncthreads();

  for (int i2 = tid; i2 < nr*D_; i2 += 256){
    int r = i2 >> 7, d = i2 & 127;
    float acc = 0.f;
    #pragma unroll 5
    for (int j = 0; j < L_; ++j) acc = fmaf(att[r][j], hs[j][d], acc);
    hlocal_out[(size_t)b*L_*D_ + (size_t)(r0+r)*D_ + d] = acc;
  }
}

// ---------------------------------------------------------------------------
// Session mean
// ---------------------------------------------------------------------------
__global__ __launch_bounds__(128) void sum_item_kernel(
    const int* __restrict__ item, const int* __restrict__ mask,
    const float* __restrict__ emb, float* __restrict__ sum_it)
{
  const int b = blockIdx.x, d = threadIdx.x;
  float acc = 0.f, cnt = 0.f;
  for (int l = 0; l < L_; ++l){
    float mf = (float)mask[b*L_ + l];
    acc = fmaf(mf, emb[(size_t)item[b*L_+l]*D_ + d], acc);
    cnt += mf;
  }
  sum_it[b*D_ + d] = acc / cnt;
}

// ---------------------------------------------------------------------------
// Neighbor expansion
// ---------------------------------------------------------------------------
__global__ void build_nbr_kernel(const int* __restrict__ src_ids, int n,
                                 const int* __restrict__ adj_all,
                                 const float* __restrict__ num_w,
                                 int* __restrict__ out_ids, float* __restrict__ out_w)
{
  int t = blockIdx.x*blockDim.x + threadIdx.x;
  if (t >= n) return;
  int parent = src_ids[t / S_];
  int s = t % S_;
  out_ids[t] = adj_all[(size_t)parent*S_ + s];
  out_w[t]   = num_w[(size_t)parent*S_ + s];
}

// ---------------------------------------------------------------------------
// emb f32 -> f16 table (A-operand gathers halve; f16 2^-11 beats old bf16)
// ---------------------------------------------------------------------------
__global__ void emb2f16_kernel(const float* __restrict__ emb,
                               _Float16* __restrict__ embh, int n4)
{
  int i = blockIdx.x*256 + threadIdx.x;
  if (i >= n4) return;
  float4 v = ((const float4*)emb)[i];
  union { _Float16 h[4]; uint2 u; } pk;
  pk.h[0] = (_Float16)v.x; pk.h[1] = (_Float16)v.y;
  pk.h[2] = (_Float16)v.z; pk.h[3] = (_Float16)v.w;
  ((uint2*)embh)[i] = pk.u;
}

// ---------------------------------------------------------------------------
// Pack gw1[hop][k<128][d] into MFMA B-frag order (f16):
// frag f = t*8+n: lane l, slot j <- gw1[k=t*32+(l>>4)*8+j][n*16+(l&15)]
// ---------------------------------------------------------------------------
__global__ void prep_gw1frag_kernel(const float* __restrict__ gw1, _Float16* __restrict__ outf){
  int idx = blockIdx.x*256 + threadIdx.x;     // 2048 = f(32) x lane(64)
  int hop = blockIdx.y;
  int lane = idx & 63, f = idx >> 6;
  int t = f >> 3, n = f & 7;
  int g4 = lane >> 4, col = lane & 15;
  const float* g1 = gw1 + (size_t)hop*129*128;
  size_t base = (size_t)hop*16384 + ((size_t)f*64 + lane)*8;
  #pragma unroll
  for (int j = 0; j < 8; ++j){
    int k = t*32 + g4*8 + j;
    outf[base + j] = (_Float16)g1[(size_t)k*128 + n*16 + col];
  }
}

// ---------------------------------------------------------------------------
// Pack gw3[hop][k<256][d] into MFMA B-frag order (f16).
// ---------------------------------------------------------------------------
__global__ void prep_gw3frag_kernel(const float* __restrict__ gw3, _Float16* __restrict__ outf){
  int idx = blockIdx.x*256 + threadIdx.x;     // 4096 = kt(8) x n(8) x lane(64)
  int hop = blockIdx.y;
  int lane = idx & 63, n = (idx >> 6) & 7, kt = idx >> 9;
  int g4 = lane >> 4, col = lane & 15;
  const float* g3 = gw3 + (size_t)hop*256*128;
  size_t base = (size_t)hop*32768 + ((size_t)(kt*8 + n)*64 + lane)*8;
  #pragma unroll
  for (int j = 0; j < 8; ++j){
    int k = kt*32 + g4*8 + j;
    outf[base + j] = (_Float16)g3[(size_t)k*128 + n*16 + col];
  }
}

// ---------------------------------------------------------------------------
// W'[hop][b] = si_b (x) gw1[hop]  folded scaled-weight, f16, frag order.
// 40 frags: f<32 regular K-blocks; f=32..39 the nw K-block (row k=128 =
// gw1_last unscaled, rest zero). Layout wg[(hop*128+b)*40 + f][lane][8].
// ---------------------------------------------------------------------------
__global__ __launch_bounds__(256) void prep_wprime_kernel(
    const float* __restrict__ gw1, const _Float16* __restrict__ gw1f,
    const float* __restrict__ sum_it, _Float16* __restrict__ wg)
{
  __shared__ float si[128];
  const int b = blockIdx.x, hop = blockIdx.y, tid = threadIdx.x;
  if (tid < 128) si[tid] = sum_it[b*D_ + tid];
  __syncthreads();
  const float* gl = gw1 + (size_t)hop*129*128 + 128*128;   // gw1_last
  _Float16* wb = wg + ((size_t)(hop*128 + b)*40)*512;

  for (int i = 0; i < 10; ++i){
    int slot = i*256 + tid;            // 2560 = 40 frags x 64 lanes
    int f = slot >> 6, l = slot & 63;
    int g4 = l >> 4, col = l & 15;
    union { _Float16 h[8]; uint4 q; } o;
    if (f < 32){
      int t = f >> 3;
      const _Float16* gf = gw1f + (size_t)hop*16384 + ((size_t)f*64 + l)*8;
      int k0 = t*32 + g4*8;
      #pragma unroll
      for (int j = 0; j < 8; ++j)
        o.h[j] = (_Float16)(si[k0+j] * (float)gf[j]);
    } else {
      int n = f - 32, d = n*16 + col;
      #pragma unroll
      for (int j = 0; j < 8; ++j) o.h[j] = (_Float16)0.f;
      if (g4 == 0) o.h[0] = (_Float16)gl[d];
    }
    *(uint4*)(wb + (size_t)slot*8) = o.q;
  }
}

// ---------------------------------------------------------------------------
// GlobalAggregator v7 (si folded into W'):
// Block = 4 waves, 16 pairs of ONE batch b (blocks-per-b = ceil(M/16), tail
// pairs clamped + store-guarded). Wave: 4 pairs as 2 iterations x 2-pair
// MFMA interleave (W' frag loads shared; lean interleave only -> ~64 acc
// regs, no R5-style spill). Stage B: A = raw f16 nv gathers (embh/out1h),
// B = W'_b frags streamed from L2; nw term folded as 5th K-block. Zero VALU
// in stage B. Scores/softmax as R8. Stage C from f16 LDS stash. Stage D
// block-coop f16 MFMA (catl) with proper __syncthreads (R8 race fixed).
// ---------------------------------------------------------------------------
template<bool USE_IDS, bool OUTF32>
__global__ __launch_bounds__(256, 2) void gagg7_kernel(
    const _Float16* __restrict__ embh,
    const int* sv_ids0, const _Float16* sv_vals0,
    const int* nv_ids0, const _Float16* nv_vals0,
    const float* nw0, void* outp0, int M0, int nbpb0, int nblk0,
    const int* sv_ids1, const _Float16* sv_vals1,
    const int* nv_ids1, const _Float16* nv_vals1,
    const float* nw1, void* outp1, int M1, int nbpb1,
    const _Float16* __restrict__ wg,
    const float* __restrict__ gw2, const _Float16* __restrict__ gw3f)
{
  __shared__ _Float16 stash[4][2][12][132];   // 25344 B (wave-private, b64-friendly)
  __shared__ _Float16 catl[16][264];          //  8448 B (block-shared)
  const int tid  = threadIdx.x;
  const int wid  = tid >> 6;
  const int lane = tid & 63;
  const int g4   = lane >> 4;
  const int col  = lane & 15;
  const bool colv = col < S_;
  const int sc_  = colv ? col : 0;

  const bool c1 = ((int)blockIdx.x >= nblk0);
  const int  blk = c1 ? (int)blockIdx.x - nblk0 : (int)blockIdx.x;
  const int*       sv_ids  = c1 ? sv_ids1  : sv_ids0;
  const _Float16*  sv_vals = c1 ? sv_vals1 : sv_vals0;
  const int*       nv_ids  = c1 ? nv_ids1  : nv_ids0;
  const _Float16*  nv_vals = c1 ? nv_vals1 : nv_vals0;
  const float*     nw      = c1 ? nw1      : nw0;
  void*            outp    = c1 ? outp1    : outp0;
  const int        M       = c1 ? M1       : M0;
  const int        nbpb    = c1 ? nbpb1    : nbpb0;

  const int b = blk / nbpb;
  const int j = blk - b*nbpb;
  const _Float16* wgb = wg + (size_t)b*40*512;

  float g2v[8];
  #pragma unroll
  for (int n = 0; n < 8; ++n) g2v[n] = gw2[n*16 + col];

  for (int it = 0; it < 2; ++it){
    const int li0 = j*16 + wid*4 + it*2;
    const int liA = li0     < M ? li0     : M-1;
    const int liB = li0 + 1 < M ? li0 + 1 : M-1;
    const int pA = b*M + liA, pB = b*M + liB;

    const _Float16* nvrowA = USE_IDS
        ? embh + (size_t)nv_ids[pA*S_ + sc_]*D_
        : nv_vals + ((size_t)pA*S_ + sc_)*D_;
    const _Float16* nvrowB = USE_IDS
        ? embh + (size_t)nv_ids[pB*S_ + sc_]*D_
        : nv_vals + ((size_t)pB*S_ + sc_)*D_;

    f32x4 accA[8], accB[8];
    #pragma unroll
    for (int n = 0; n < 8; ++n){
      accA[n] = (f32x4){0.f,0.f,0.f,0.f};
      accB[n] = (f32x4){0.f,0.f,0.f,0.f};
    }

    #pragma unroll
    for (int t = 0; t < 4; ++t){
      half8 afA = {0,0,0,0,0,0,0,0};
      half8 afB = {0,0,0,0,0,0,0,0};
      if (colv){
        afA = *(const half8*)(nvrowA + t*32 + g4*8);
        afB = *(const half8*)(nvrowB + t*32 + g4*8);
        union { half8 v; uint2 q[2]; } ua, ub;
        ua.v = afA; ub.v = afB;
        _Float16* sA = &stash[wid][0][col][t*32 + g4*8];
        _Float16* sB = &stash[wid][1][col][t*32 + g4*8];
        *(uint2*)sA       = ua.q[0];
        *(uint2*)(sA + 4) = ua.q[1];
        *(uint2*)sB       = ub.q[0];
        *(uint2*)(sB + 4) = ub.q[1];
      }
      #pragma unroll
      for (int n = 0; n < 8; ++n){
        half8 wf = *(const half8*)(wgb + ((size_t)(t*8+n)*64 + lane)*8);
        accA[n] = __builtin_amdgcn_mfma_f32_16x16x32_f16(afA, wf, accA[n], 0, 0, 0);
        accB[n] = __builtin_amdgcn_mfma_f32_16x16x32_f16(afB, wf, accB[n], 0, 0, 0);
      }
    }
    { // nw K-block (k=128): A col0 = nw[s], B row0 = gw1_last
      half8 afA = {0,0,0,0,0,0,0,0};
      half8 afB = {0,0,0,0,0,0,0,0};
      if (colv && g4 == 0){
        afA[0] = (_Float16)nw[pA*S_ + col];
        afB[0] = (_Float16)nw[pB*S_ + col];
      }
      #pragma unroll
      for (int n = 0; n < 8; ++n){
        half8 wf = *(const half8*)(wgb + ((size_t)(32+n)*64 + lane)*8);
        accA[n] = __builtin_amdgcn_mfma_f32_16x16x32_f16(afA, wf, accA[n], 0, 0, 0);
        accB[n] = __builtin_amdgcn_mfma_f32_16x16x32_f16(afB, wf, accB[n], 0, 0, 0);
      }
    }

    // -------- finish both pairs: scores -> softmax -> stage C -> catl ------
    auto finish_pair = [&](const f32x4 (&acc)[8], int p, int u, int row){
      float sc4[4];
      #pragma unroll
      for (int r = 0; r < 4; ++r){
        float pr = 0.f;
        #pragma unroll
        for (int n = 0; n < 8; ++n)
          pr = fmaf(lrelu(acc[n][r]), g2v[n], pr);
        pr += __shfl_xor(pr, 1); pr += __shfl_xor(pr, 2);
        pr += __shfl_xor(pr, 4); pr += __shfl_xor(pr, 8);
        sc4[r] = pr;
      }
      float w[S_];
      {
        float ss[S_];
        #pragma unroll
        for (int grp = 0; grp < 3; ++grp)
          #pragma unroll
          for (int r = 0; r < 4; ++r)
            ss[grp*4 + r] = __shfl(sc4[r], grp*16);
        float m = -1e30f;
        #pragma unroll
        for (int s = 0; s < S_; ++s) m = fmaxf(m, ss[s]);
        float sum = 0.f;
        #pragma unroll
        for (int s = 0; s < S_; ++s){ ss[s] = expf(ss[s]-m); sum += ss[s]; }
        float inv = 1.f/sum;
        #pragma unroll
        for (int s = 0; s < S_; ++s) w[s] = ss[s]*inv;
      }
      float aggx = 0.f, aggy = 0.f;
      #pragma unroll
      for (int s = 0; s < S_; ++s){
        union { unsigned q; _Float16 h[2]; } v;
        v.q = *(const unsigned*)&stash[wid][u][s][2*lane];
        aggx = fmaf(w[s], (float)v.h[0], aggx);
        aggy = fmaf(w[s], (float)v.h[1], aggy);
      }
      const _Float16* svrow = USE_IDS ? embh + (size_t)sv_ids[p]*D_
                                      : sv_vals + (size_t)p*D_;
      *(unsigned*)&catl[row][2*lane] = *(const unsigned*)(svrow + 2*lane);
      union { unsigned q; _Float16 h[2]; } pk;
      pk.h[0] = (_Float16)aggx; pk.h[1] = (_Float16)aggy;
      *(unsigned*)&catl[row][D_ + 2*lane] = pk.q;
    };
    finish_pair(accA, pA, 0, wid*4 + it*2);
    finish_pair(accB, pB, 1, wid*4 + it*2 + 1);
  }

  __syncthreads();   // catl is block-shared (R8 raced here; fixed)

  // -------- stage D: [16x256]@[256x128] f16 MFMA, wave owns 2 n-frags -----
  const half8* g3fp = (const half8*)gw3f;
  f32x4 dacc[2];
  dacc[0] = (f32x4){0.f,0.f,0.f,0.f};
  dacc[1] = (f32x4){0.f,0.f,0.f,0.f};

  #pragma unroll
  for (int kt = 0; kt < 8; ++kt){
    half8 afr = *(const half8*)&catl[col][kt*32 + g4*8];
    #pragma unroll
    for (int nn = 0; nn < 2; ++nn){
      int n = wid*2 + nn;
      dacc[nn] = __builtin_amdgcn_mfma_f32_16x16x32_f16(afr, g3fp[(kt*8+n)*64 + lane], dacc[nn], 0, 0, 0);
    }
  }

  #pragma unroll
  for (int nn = 0; nn < 2; ++nn){
    int n = wid*2 + nn;
    #pragma unroll
    for (int r = 0; r < 4; ++r){
      int li = j*16 + g4*4 + r;
      if (li < M){
        size_t off = (size_t)(b*M + li)*D_ + n*16 + col;
        float v = fmaxf(dacc[nn][r], 0.f);
        if (OUTF32) ((float*)outp)[off] = v;
        else        ((_Float16*)outp)[off] = (_Float16)v;
      }
    }
  }
}

// ---------------------------------------------------------------------------
// output = h_local + s_global
// ---------------------------------------------------------------------------
__global__ void final_add_kernel(float* __restrict__ dout){
  int i = blockIdx.x*blockDim.x + threadIdx.x;
  const int n4 = (B_*L_*D_)/4;
  if (i < n4){
    float4* o = (float4*)dout;
    const float4* s = (const float4*)(dout + B_*L_*D_);
    float4 a = o[i], b = s[i];
    a.x += b.x; a.y += b.y; a.z += b.z; a.w += b.w;
    o[i] = a;
  }
}

extern "C" void kernel_launch(void* const* d_in, const int* in_sizes, int n_in,
                              void* d_out, int out_size, void* d_ws, size_t ws_size,
                              hipStream_t stream)
{
  const int*   inputs  = (const int*)  d_in[0];
  const int*   adj     = (const int*)  d_in[1];
  const int*   mask    = (const int*)  d_in[2];
  const int*   item    = (const int*)  d_in[3];
  const float* emb     = (const float*)d_in[4];
  const int*   adj_all = (const int*)  d_in[5];
  const float* num_w   = (const float*)d_in[6];
  const float* a0      = (const float*)d_in[7];
  const float* a1      = (const float*)d_in[8];
  const float* a2      = (const float*)d_in[9];
  const float* a3      = (const float*)d_in[10];
  const float* gw1     = (const float*)d_in[11];  // [2][129][128]
  const float* gw2     = (const float*)d_in[12];  // [2][128]
  const float* gw3     = (const float*)d_in[13];  // [2][256][128]

  float* out     = (float*)d_out;
  float* hlocal  = out;
  float* sglobal = out + B_*L_*D_;

  char* ws = (char*)d_ws;
  size_t off = 0;
  auto alloc = [&](size_t bytes)->char*{
    char* pp = ws + off; off += (bytes + 255) & ~(size_t)255; return pp;
  };
  float*    sum_it = (float*)alloc((size_t)B_*D_*sizeof(float));
  int*      n1     = (int*)  alloc((size_t)B_*L_*S_*sizeof(int));
  float*    w0     = (float*)alloc((size_t)B_*L_*S_*sizeof(float));
  int*      n2     = (int*)  alloc((size_t)B_*L_*S_*S_*sizeof(int));
  float*    w1     = (float*)alloc((size_t)B_*L_*S_*S_*sizeof(float));
  _Float16* out0h  = (_Float16*)alloc((size_t)B_*L_*D_*sizeof(_Float16));
  _Float16* out1h  = (_Float16*)alloc((size_t)B_*L_*S_*D_*sizeof(_Float16));
  _Float16* embh   = (_Float16*)alloc((size_t)100000*D_*sizeof(_Float16));
  _Float16* gw1f   = (_Float16*)alloc((size_t)2*16384*sizeof(_Float16));
  _Float16* gw3f   = (_Float16*)alloc((size_t)2*32768*sizeof(_Float16));
  _Float16* wgAll  = (_Float16*)alloc((size_t)2*128*40*512*sizeof(_Float16)); // 10.5MB

  emb2f16_kernel<<<(100000*D_/4 + 255)/256, 256, 0, stream>>>(emb, embh, 100000*D_/4);
  prep_gw1frag_kernel<<<dim3(8,2), 256, 0, stream>>>(gw1, gw1f);
  prep_gw3frag_kernel<<<dim3(16,2), 256, 0, stream>>>(gw3, gw3f);
  local_agg_kernel<<<dim3(B_,4), 256, 0, stream>>>(inputs, adj, emb, a0, a1, a2, a3, hlocal);
  sum_item_kernel<<<B_, 128, 0, stream>>>(item, mask, emb, sum_it);
  build_nbr_kernel<<<(B_*L_*S_ + 255)/256, 256, 0, stream>>>(inputs, B_*L_*S_, adj_all, num_w, n1, w0);
  build_nbr_kernel<<<(B_*L_*S_*S_ + 255)/256, 256, 0, stream>>>(n1, B_*L_*S_*S_, adj_all, num_w, n2, w1);
  prep_wprime_kernel<<<dim3(B_,2), 256, 0, stream>>>(gw1, gw1f, sum_it, wgAll);

  // Fused hop0: cfg0 = pass A (ids, emb -> out0h, M=50, nbpb=4, 512 blocks)
  //             cfg1 = pass B (ids, emb -> out1h, M=600, nbpb=38, 4864 blocks)
  {
    const int nblkA = B_*4;        // 512
    const int nblkB = B_*38;       // 4864
    gagg7_kernel<true,false><<<nblkA + nblkB, 256, 0, stream>>>(
        embh,
        inputs, nullptr, n1, nullptr, w0, out0h, L_,   4, nblkA,
        n1,     nullptr, n2, nullptr, w1, out1h, L_*S_, 38,
        wgAll, gw2, gw3f);
  }
  // hop1 (pass C): vals = out0h/out1h, hop1 W', f32 out -> sglobal
  {
    const int nblkC = B_*4;        // 512
    gagg7_kernel<false,true><<<nblkC, 256, 0, stream>>>(
        embh,
        nullptr, out0h, nullptr, out1h, w0, sglobal, L_, 4, nblkC,
        nullptr, out0h, nullptr, out1h, w0, sglobal, L_, 4,
        wgAll + (size_t)128*40*512, gw2 + 128, gw3f + 32768);
  }

  final_add_kernel<<<((B_*L_*D_/4) + 255)/256, 256, 0, stream>>>(out);
}

// Round 10
// 263.961 us; speedup vs baseline: 1.7201x; 1.7201x over previous
//
#include <hip/hip_runtime.h>
#include <hip/hip_bf16.h>
#include <math.h>

#define B_ 128
#define L_ 50
#define D_ 128
#define S_ 12
#define NEG_INF_ -9e15f

typedef __attribute__((ext_vector_type(8))) _Float16 half8;
typedef __attribute__((ext_vector_type(4))) float f32x4;

static __device__ __forceinline__ float lrelu(float x){ return fmaxf(x, 0.2f*x); }

// ---------------------------------------------------------------------------
// Local aggregator: 4-edge-type GAT. Grid (B, 4).
// ---------------------------------------------------------------------------
__global__ __launch_bounds__(256) void local_agg_kernel(
    const int* __restrict__ inputs, const int* __restrict__ adj,
    const float* __restrict__ emb,
    const float* __restrict__ a0, const float* __restrict__ a1,
    const float* __restrict__ a2, const float* __restrict__ a3,
    float* __restrict__ hlocal_out)
{
  __shared__ float hs[L_][129];
  __shared__ float alds[4][129];
  __shared__ float att[13][51];
  const int b = blockIdx.x, tid = threadIdx.x;
  const int r0 = blockIdx.y * 13;
  const int nr = (L_ - r0) < 13 ? (L_ - r0) : 13;

  if (tid < 128){
    alds[0][tid] = a0[tid]; alds[1][tid] = a1[tid];
    alds[2][tid] = a2[tid]; alds[3][tid] = a3[tid];
  }
  for (int i = tid; i < L_*D_; i += 256){
    int r = i >> 7, d = i & 127;
    hs[r][d] = emb[(size_t)inputs[b*L_ + r]*D_ + d];
  }
  __syncthreads();

  for (int pth = tid; pth < nr*L_; pth += 256){
    int i = pth / L_, j = pth % L_;
    int at = adj[b*L_*L_ + (r0+i)*L_ + j];
    float lg = NEG_INF_;
    if (at >= 1 && at <= 4){
      const float* av = alds[at-1];
      float acc = 0.f;
      #pragma unroll 4
      for (int d = 0; d < D_; ++d) acc = fmaf(hs[r0+i][d]*hs[j][d], av[d], acc);
      lg = lrelu(acc);
    }
    att[i][j] = lg;
  }
  __syncthreads();

  if (tid < nr){
    float m = -1e30f;
    for (int j = 0; j < L_; ++j) m = fmaxf(m, att[tid][j]);
    float sum = 0.f;
    for (int j = 0; j < L_; ++j){ float e = expf(att[tid][j]-m); att[tid][j] = e; sum += e; }
    float inv = 1.f/sum;
    for (int j = 0; j < L_; ++j) att[tid][j] *= inv;
  }
  __syncthreads();

  for (int i2 = tid; i2 < nr*D_; i2 += 256){
    int r = i2 >> 7, d = i2 & 127;
    float acc = 0.f;
    #pragma unroll 5
    for (int j = 0; j < L_; ++j) acc = fmaf(att[r][j], hs[j][d], acc);
    hlocal_out[(size_t)b*L_*D_ + (size_t)(r0+r)*D_ + d] = acc;
  }
}

// ---------------------------------------------------------------------------
// Session mean
// ---------------------------------------------------------------------------
__global__ __launch_bounds__(128) void sum_item_kernel(
    const int* __restrict__ item, const int* __restrict__ mask,
    const float* __restrict__ emb, float* __restrict__ sum_it)
{
  const int b = blockIdx.x, d = threadIdx.x;
  float acc = 0.f, cnt = 0.f;
  for (int l = 0; l < L_; ++l){
    float mf = (float)mask[b*L_ + l];
    acc = fmaf(mf, emb[(size_t)item[b*L_+l]*D_ + d], acc);
    cnt += mf;
  }
  sum_it[b*D_ + d] = acc / cnt;
}

// ---------------------------------------------------------------------------
// Neighbor expansion
// ---------------------------------------------------------------------------
__global__ void build_nbr_kernel(const int* __restrict__ src_ids, int n,
                                 const int* __restrict__ adj_all,
                                 const float* __restrict__ num_w,
                                 int* __restrict__ out_ids, float* __restrict__ out_w)
{
  int t = blockIdx.x*blockDim.x + threadIdx.x;
  if (t >= n) return;
  int parent = src_ids[t / S_];
  int s = t % S_;
  out_ids[t] = adj_all[(size_t)parent*S_ + s];
  out_w[t]   = num_w[(size_t)parent*S_ + s];
}

// ---------------------------------------------------------------------------
// emb f32 -> f16 table
// ---------------------------------------------------------------------------
__global__ void emb2f16_kernel(const float* __restrict__ emb,
                               _Float16* __restrict__ embh, int n4)
{
  int i = blockIdx.x*256 + threadIdx.x;
  if (i >= n4) return;
  float4 v = ((const float4*)emb)[i];
  union { _Float16 h[4]; uint2 u; } pk;
  pk.h[0] = (_Float16)v.x; pk.h[1] = (_Float16)v.y;
  pk.h[2] = (_Float16)v.z; pk.h[3] = (_Float16)v.w;
  ((uint2*)embh)[i] = pk.u;
}

// ---------------------------------------------------------------------------
// Pack gw1[hop][k<128][d] into MFMA B-frag order (f16).
// ---------------------------------------------------------------------------
__global__ void prep_gw1frag_kernel(const float* __restrict__ gw1, _Float16* __restrict__ outf){
  int idx = blockIdx.x*256 + threadIdx.x;     // 2048 = f(32) x lane(64)
  int hop = blockIdx.y;
  int lane = idx & 63, f = idx >> 6;
  int t = f >> 3, n = f & 7;
  int g4 = lane >> 4, col = lane & 15;
  const float* g1 = gw1 + (size_t)hop*129*128;
  size_t base = (size_t)hop*16384 + ((size_t)f*64 + lane)*8;
  #pragma unroll
  for (int j = 0; j < 8; ++j){
    int k = t*32 + g4*8 + j;
    outf[base + j] = (_Float16)g1[(size_t)k*128 + n*16 + col];
  }
}

// ---------------------------------------------------------------------------
// Pack gw3[hop][k<256][d] into MFMA B-frag order (f16).
// ---------------------------------------------------------------------------
__global__ void prep_gw3frag_kernel(const float* __restrict__ gw3, _Float16* __restrict__ outf){
  int idx = blockIdx.x*256 + threadIdx.x;     // 4096 = kt(8) x n(8) x lane(64)
  int hop = blockIdx.y;
  int lane = idx & 63, n = (idx >> 6) & 7, kt = idx >> 9;
  int g4 = lane >> 4, col = lane & 15;
  const float* g3 = gw3 + (size_t)hop*256*128;
  size_t base = (size_t)hop*32768 + ((size_t)(kt*8 + n)*64 + lane)*8;
  #pragma unroll
  for (int j = 0; j < 8; ++j){
    int k = kt*32 + g4*8 + j;
    outf[base + j] = (_Float16)g3[(size_t)k*128 + n*16 + col];
  }
}

// ---------------------------------------------------------------------------
// W'[hop][b] = si_b (x) gw1[hop], f16, frag order; 40 frags (32 + nw block).
// ---------------------------------------------------------------------------
__global__ __launch_bounds__(256) void prep_wprime_kernel(
    const float* __restrict__ gw1, const _Float16* __restrict__ gw1f,
    const float* __restrict__ sum_it, _Float16* __restrict__ wg)
{
  __shared__ float si[128];
  const int b = blockIdx.x, hop = blockIdx.y, tid = threadIdx.x;
  if (tid < 128) si[tid] = sum_it[b*D_ + tid];
  __syncthreads();
  const float* gl = gw1 + (size_t)hop*129*128 + 128*128;   // gw1_last
  _Float16* wb = wg + ((size_t)(hop*128 + b)*40)*512;

  for (int i = 0; i < 10; ++i){
    int slot = i*256 + tid;            // 2560 = 40 frags x 64 lanes
    int f = slot >> 6, l = slot & 63;
    int g4 = l >> 4, col = l & 15;
    union { _Float16 h[8]; uint4 q; } o;
    if (f < 32){
      int t = f >> 3;
      const _Float16* gf = gw1f + (size_t)hop*16384 + ((size_t)f*64 + l)*8;
      int k0 = t*32 + g4*8;
      #pragma unroll
      for (int j = 0; j < 8; ++j)
        o.h[j] = (_Float16)(si[k0+j] * (float)gf[j]);
    } else {
      int n = f - 32, d = n*16 + col;
      #pragma unroll
      for (int j = 0; j < 8; ++j) o.h[j] = (_Float16)0.f;
      if (g4 == 0) o.h[0] = (_Float16)gl[d];
    }
    *(uint4*)(wb + (size_t)slot*8) = o.q;
  }
}

// ---------------------------------------------------------------------------
// GlobalAggregator v8 (= v7 minus the 2-pair interleave).
// R5+R9 lesson (twice confirmed): ANY 2-pair acc interleave spills scratch
// (WRITE 180-400MB signature). Single pair per iteration, 4 per wave.
// Stage B: A = raw f16 nv gathers, B = W'_b frags (si folded; zero VALU),
// nw folded as 5th K-block. Stage C from f16 LDS stash. Stage D block-coop
// f16 MFMA over catl[16][264] with __syncthreads.
// ---------------------------------------------------------------------------
template<bool USE_IDS, bool OUTF32>
__global__ __launch_bounds__(256, 2) void gagg8_kernel(
    const _Float16* __restrict__ embh,
    const int* sv_ids0, const _Float16* sv_vals0,
    const int* nv_ids0, const _Float16* nv_vals0,
    const float* nw0, void* outp0, int M0, int nbpb0, int nblk0,
    const int* sv_ids1, const _Float16* sv_vals1,
    const int* nv_ids1, const _Float16* nv_vals1,
    const float* nw1, void* outp1, int M1, int nbpb1,
    const _Float16* __restrict__ wg,
    const float* __restrict__ gw2, const _Float16* __restrict__ gw3f)
{
  __shared__ _Float16 stash[4][12][132];      // 12672 B (wave-private)
  __shared__ _Float16 catl[16][264];          //  8448 B (block-shared)
  const int tid  = threadIdx.x;
  const int wid  = tid >> 6;
  const int lane = tid & 63;
  const int g4   = lane >> 4;
  const int col  = lane & 15;
  const bool colv = col < S_;
  const int sc_  = colv ? col : 0;

  const bool c1 = ((int)blockIdx.x >= nblk0);
  const int  blk = c1 ? (int)blockIdx.x - nblk0 : (int)blockIdx.x;
  const int*       sv_ids  = c1 ? sv_ids1  : sv_ids0;
  const _Float16*  sv_vals = c1 ? sv_vals1 : sv_vals0;
  const int*       nv_ids  = c1 ? nv_ids1  : nv_ids0;
  const _Float16*  nv_vals = c1 ? nv_vals1 : nv_vals0;
  const float*     nw      = c1 ? nw1      : nw0;
  void*            outp    = c1 ? outp1    : outp0;
  const int        M       = c1 ? M1       : M0;
  const int        nbpb    = c1 ? nbpb1    : nbpb0;

  const int b = blk / nbpb;
  const int j = blk - b*nbpb;
  const _Float16* wgb = wg + (size_t)b*40*512;

  float g2v[8];
  #pragma unroll
  for (int n = 0; n < 8; ++n) g2v[n] = gw2[n*16 + col];

  for (int np = 0; np < 4; ++np){
    const int li0 = j*16 + wid*4 + np;
    const int li  = li0 < M ? li0 : M-1;
    const int p   = b*M + li;

    const _Float16* nvrow = USE_IDS
        ? embh + (size_t)nv_ids[p*S_ + sc_]*D_
        : nv_vals + ((size_t)p*S_ + sc_)*D_;

    f32x4 acc[8];
    #pragma unroll
    for (int n = 0; n < 8; ++n) acc[n] = (f32x4){0.f,0.f,0.f,0.f};

    #pragma unroll
    for (int t = 0; t < 4; ++t){
      half8 af = {0,0,0,0,0,0,0,0};
      if (colv){
        af = *(const half8*)(nvrow + t*32 + g4*8);
        union { half8 v; uint2 q[2]; } ua;
        ua.v = af;
        _Float16* sp = &stash[wid][col][t*32 + g4*8];
        *(uint2*)sp       = ua.q[0];
        *(uint2*)(sp + 4) = ua.q[1];
      }
      #pragma unroll
      for (int n = 0; n < 8; ++n){
        half8 wf = *(const half8*)(wgb + ((size_t)(t*8+n)*64 + lane)*8);
        acc[n] = __builtin_amdgcn_mfma_f32_16x16x32_f16(af, wf, acc[n], 0, 0, 0);
      }
    }
    { // nw K-block (k=128): A col0 = nw[s], B row0 = gw1_last
      half8 af = {0,0,0,0,0,0,0,0};
      if (colv && g4 == 0) af[0] = (_Float16)nw[p*S_ + col];
      #pragma unroll
      for (int n = 0; n < 8; ++n){
        half8 wf = *(const half8*)(wgb + ((size_t)(32+n)*64 + lane)*8);
        acc[n] = __builtin_amdgcn_mfma_f32_16x16x32_f16(af, wf, acc[n], 0, 0, 0);
      }
    }

    // -------- scores -> softmax -> stage C -> catl row ---------------------
    float sc4[4];
    #pragma unroll
    for (int r = 0; r < 4; ++r){
      float pr = 0.f;
      #pragma unroll
      for (int n = 0; n < 8; ++n)
        pr = fmaf(lrelu(acc[n][r]), g2v[n], pr);
      pr += __shfl_xor(pr, 1); pr += __shfl_xor(pr, 2);
      pr += __shfl_xor(pr, 4); pr += __shfl_xor(pr, 8);
      sc4[r] = pr;
    }
    float w[S_];
    {
      float ss[S_];
      #pragma unroll
      for (int grp = 0; grp < 3; ++grp)
        #pragma unroll
        for (int r = 0; r < 4; ++r)
          ss[grp*4 + r] = __shfl(sc4[r], grp*16);
      float m = -1e30f;
      #pragma unroll
      for (int s = 0; s < S_; ++s) m = fmaxf(m, ss[s]);
      float sum = 0.f;
      #pragma unroll
      for (int s = 0; s < S_; ++s){ ss[s] = expf(ss[s]-m); sum += ss[s]; }
      float inv = 1.f/sum;
      #pragma unroll
      for (int s = 0; s < S_; ++s) w[s] = ss[s]*inv;
    }
    float aggx = 0.f, aggy = 0.f;
    #pragma unroll
    for (int s = 0; s < S_; ++s){
      union { unsigned q; _Float16 h[2]; } v;
      v.q = *(const unsigned*)&stash[wid][s][2*lane];
      aggx = fmaf(w[s], (float)v.h[0], aggx);
      aggy = fmaf(w[s], (float)v.h[1], aggy);
    }
    const _Float16* svrow = USE_IDS ? embh + (size_t)sv_ids[p]*D_
                                    : sv_vals + (size_t)p*D_;
    const int row = wid*4 + np;
    *(unsigned*)&catl[row][2*lane] = *(const unsigned*)(svrow + 2*lane);
    union { unsigned q; _Float16 h[2]; } pk;
    pk.h[0] = (_Float16)aggx; pk.h[1] = (_Float16)aggy;
    *(unsigned*)&catl[row][D_ + 2*lane] = pk.q;
  }

  __syncthreads();   // catl is block-shared

  // -------- stage D: [16x256]@[256x128] f16 MFMA, wave owns 2 n-frags -----
  const half8* g3fp = (const half8*)gw3f;
  f32x4 dacc[2];
  dacc[0] = (f32x4){0.f,0.f,0.f,0.f};
  dacc[1] = (f32x4){0.f,0.f,0.f,0.f};

  #pragma unroll
  for (int kt = 0; kt < 8; ++kt){
    half8 afr = *(const half8*)&catl[col][kt*32 + g4*8];
    #pragma unroll
    for (int nn = 0; nn < 2; ++nn){
      int n = wid*2 + nn;
      dacc[nn] = __builtin_amdgcn_mfma_f32_16x16x32_f16(afr, g3fp[(kt*8+n)*64 + lane], dacc[nn], 0, 0, 0);
    }
  }

  #pragma unroll
  for (int nn = 0; nn < 2; ++nn){
    int n = wid*2 + nn;
    #pragma unroll
    for (int r = 0; r < 4; ++r){
      int li = j*16 + g4*4 + r;
      if (li < M){
        size_t off = (size_t)(b*M + li)*D_ + n*16 + col;
        float v = fmaxf(dacc[nn][r], 0.f);
        if (OUTF32) ((float*)outp)[off] = v;
        else        ((_Float16*)outp)[off] = (_Float16)v;
      }
    }
  }
}

// ---------------------------------------------------------------------------
// output = h_local + s_global
// ---------------------------------------------------------------------------
__global__ void final_add_kernel(float* __restrict__ dout){
  int i = blockIdx.x*blockDim.x + threadIdx.x;
  const int n4 = (B_*L_*D_)/4;
  if (i < n4){
    float4* o = (float4*)dout;
    const float4* s = (const float4*)(dout + B_*L_*D_);
    float4 a = o[i], b = s[i];
    a.x += b.x; a.y += b.y; a.z += b.z; a.w += b.w;
    o[i] = a;
  }
}

extern "C" void kernel_launch(void* const* d_in, const int* in_sizes, int n_in,
                              void* d_out, int out_size, void* d_ws, size_t ws_size,
                              hipStream_t stream)
{
  const int*   inputs  = (const int*)  d_in[0];
  const int*   adj     = (const int*)  d_in[1];
  const int*   mask    = (const int*)  d_in[2];
  const int*   item    = (const int*)  d_in[3];
  const float* emb     = (const float*)d_in[4];
  const int*   adj_all = (const int*)  d_in[5];
  const float* num_w   = (const float*)d_in[6];
  const float* a0      = (const float*)d_in[7];
  const float* a1      = (const float*)d_in[8];
  const float* a2      = (const float*)d_in[9];
  const float* a3      = (const float*)d_in[10];
  const float* gw1     = (const float*)d_in[11];  // [2][129][128]
  const float* gw2     = (const float*)d_in[12];  // [2][128]
  const float* gw3     = (const float*)d_in[13];  // [2][256][128]

  float* out     = (float*)d_out;
  float* hlocal  = out;
  float* sglobal = out + B_*L_*D_;

  char* ws = (char*)d_ws;
  size_t off = 0;
  auto alloc = [&](size_t bytes)->char*{
    char* pp = ws + off; off += (bytes + 255) & ~(size_t)255; return pp;
  };
  float*    sum_it = (float*)alloc((size_t)B_*D_*sizeof(float));
  int*      n1     = (int*)  alloc((size_t)B_*L_*S_*sizeof(int));
  float*    w0     = (float*)alloc((size_t)B_*L_*S_*sizeof(float));
  int*      n2     = (int*)  alloc((size_t)B_*L_*S_*S_*sizeof(int));
  float*    w1     = (float*)alloc((size_t)B_*L_*S_*S_*sizeof(float));
  _Float16* out0h  = (_Float16*)alloc((size_t)B_*L_*D_*sizeof(_Float16));
  _Float16* out1h  = (_Float16*)alloc((size_t)B_*L_*S_*D_*sizeof(_Float16));
  _Float16* embh   = (_Float16*)alloc((size_t)100000*D_*sizeof(_Float16));
  _Float16* gw1f   = (_Float16*)alloc((size_t)2*16384*sizeof(_Float16));
  _Float16* gw3f   = (_Float16*)alloc((size_t)2*32768*sizeof(_Float16));
  _Float16* wgAll  = (_Float16*)alloc((size_t)2*128*40*512*sizeof(_Float16)); // 10.5MB

  emb2f16_kernel<<<(100000*D_/4 + 255)/256, 256, 0, stream>>>(emb, embh, 100000*D_/4);
  prep_gw1frag_kernel<<<dim3(8,2), 256, 0, stream>>>(gw1, gw1f);
  prep_gw3frag_kernel<<<dim3(16,2), 256, 0, stream>>>(gw3, gw3f);
  local_agg_kernel<<<dim3(B_,4), 256, 0, stream>>>(inputs, adj, emb, a0, a1, a2, a3, hlocal);
  sum_item_kernel<<<B_, 128, 0, stream>>>(item, mask, emb, sum_it);
  build_nbr_kernel<<<(B_*L_*S_ + 255)/256, 256, 0, stream>>>(inputs, B_*L_*S_, adj_all, num_w, n1, w0);
  build_nbr_kernel<<<(B_*L_*S_*S_ + 255)/256, 256, 0, stream>>>(n1, B_*L_*S_*S_, adj_all, num_w, n2, w1);
  prep_wprime_kernel<<<dim3(B_,2), 256, 0, stream>>>(gw1, gw1f, sum_it, wgAll);

  // Fused hop0: cfg0 = pass A (ids, emb -> out0h, M=50, nbpb=4, 512 blocks)
  //             cfg1 = pass B (ids, emb -> out1h, M=600, nbpb=38, 4864 blocks)
  {
    const int nblkA = B_*4;        // 512
    const int nblkB = B_*38;       // 4864
    gagg8_kernel<true,false><<<nblkA + nblkB, 256, 0, stream>>>(
        embh,
        inputs, nullptr, n1, nullptr, w0, out0h, L_,   4, nblkA,
        n1,     nullptr, n2, nullptr, w1, out1h, L_*S_, 38,
        wgAll, gw2, gw3f);
  }
  // hop1 (pass C): vals = out0h/out1h, hop1 W', f32 out -> sglobal
  {
    const int nblkC = B_*4;        // 512
    gagg8_kernel<false,true><<<nblkC, 256, 0, stream>>>(
        embh,
        nullptr, out0h, nullptr, out1h, w0, sglobal, L_, 4, nblkC,
        nullptr, out0h, nullptr, out1h, w0, sglobal, L_, 4,
        wgAll + (size_t)128*40*512, gw2 + 128, gw3f + 32768);
  }

  final_add_kernel<<<((B_*L_*D_/4) + 255)/256, 256, 0, stream>>>(out);
}

// Round 11
// 256.621 us; speedup vs baseline: 1.7693x; 1.0286x over previous
//
#include <hip/hip_runtime.h>
#include <hip/hip_bf16.h>
#include <math.h>

#define B_ 128
#define L_ 50
#define D_ 128
#define S_ 12
#define NEG_INF_ -9e15f

typedef __attribute__((ext_vector_type(8))) _Float16 half8;
typedef __attribute__((ext_vector_type(4))) float f32x4;

static __device__ __forceinline__ float lrelu(float x){ return fmaxf(x, 0.2f*x); }

// ---------------------------------------------------------------------------
// Local aggregator: 4-edge-type GAT. Grid (B, 4).
// ---------------------------------------------------------------------------
__global__ __launch_bounds__(256) void local_agg_kernel(
    const int* __restrict__ inputs, const int* __restrict__ adj,
    const float* __restrict__ emb,
    const float* __restrict__ a0, const float* __restrict__ a1,
    const float* __restrict__ a2, const float* __restrict__ a3,
    float* __restrict__ hlocal_out)
{
  __shared__ float hs[L_][129];
  __shared__ float alds[4][129];
  __shared__ float att[13][51];
  const int b = blockIdx.x, tid = threadIdx.x;
  const int r0 = blockIdx.y * 13;
  const int nr = (L_ - r0) < 13 ? (L_ - r0) : 13;

  if (tid < 128){
    alds[0][tid] = a0[tid]; alds[1][tid] = a1[tid];
    alds[2][tid] = a2[tid]; alds[3][tid] = a3[tid];
  }
  for (int i = tid; i < L_*D_; i += 256){
    int r = i >> 7, d = i & 127;
    hs[r][d] = emb[(size_t)inputs[b*L_ + r]*D_ + d];
  }
  __syncthreads();

  for (int pth = tid; pth < nr*L_; pth += 256){
    int i = pth / L_, j = pth % L_;
    int at = adj[b*L_*L_ + (r0+i)*L_ + j];
    float lg = NEG_INF_;
    if (at >= 1 && at <= 4){
      const float* av = alds[at-1];
      float acc = 0.f;
      #pragma unroll 4
      for (int d = 0; d < D_; ++d) acc = fmaf(hs[r0+i][d]*hs[j][d], av[d], acc);
      lg = lrelu(acc);
    }
    att[i][j] = lg;
  }
  __syncthreads();

  if (tid < nr){
    float m = -1e30f;
    for (int j = 0; j < L_; ++j) m = fmaxf(m, att[tid][j]);
    float sum = 0.f;
    for (int j = 0; j < L_; ++j){ float e = expf(att[tid][j]-m); att[tid][j] = e; sum += e; }
    float inv = 1.f/sum;
    for (int j = 0; j < L_; ++j) att[tid][j] *= inv;
  }
  __syncthreads();

  for (int i2 = tid; i2 < nr*D_; i2 += 256){
    int r = i2 >> 7, d = i2 & 127;
    float acc = 0.f;
    #pragma unroll 5
    for (int j = 0; j < L_; ++j) acc = fmaf(att[r][j], hs[j][d], acc);
    hlocal_out[(size_t)b*L_*D_ + (size_t)(r0+r)*D_ + d] = acc;
  }
}

// ---------------------------------------------------------------------------
// Session mean
// ---------------------------------------------------------------------------
__global__ __launch_bounds__(128) void sum_item_kernel(
    const int* __restrict__ item, const int* __restrict__ mask,
    const float* __restrict__ emb, float* __restrict__ sum_it)
{
  const int b = blockIdx.x, d = threadIdx.x;
  float acc = 0.f, cnt = 0.f;
  for (int l = 0; l < L_; ++l){
    float mf = (float)mask[b*L_ + l];
    acc = fmaf(mf, emb[(size_t)item[b*L_+l]*D_ + d], acc);
    cnt += mf;
  }
  sum_it[b*D_ + d] = acc / cnt;
}

// ---------------------------------------------------------------------------
// Neighbor expansion
// ---------------------------------------------------------------------------
__global__ void build_nbr_kernel(const int* __restrict__ src_ids, int n,
                                 const int* __restrict__ adj_all,
                                 const float* __restrict__ num_w,
                                 int* __restrict__ out_ids, float* __restrict__ out_w)
{
  int t = blockIdx.x*blockDim.x + threadIdx.x;
  if (t >= n) return;
  int parent = src_ids[t / S_];
  int s = t % S_;
  out_ids[t] = adj_all[(size_t)parent*S_ + s];
  out_w[t]   = num_w[(size_t)parent*S_ + s];
}

// ---------------------------------------------------------------------------
// emb f32 -> f16 table
// ---------------------------------------------------------------------------
__global__ void emb2f16_kernel(const float* __restrict__ emb,
                               _Float16* __restrict__ embh, int n4)
{
  int i = blockIdx.x*256 + threadIdx.x;
  if (i >= n4) return;
  float4 v = ((const float4*)emb)[i];
  union { _Float16 h[4]; uint2 u; } pk;
  pk.h[0] = (_Float16)v.x; pk.h[1] = (_Float16)v.y;
  pk.h[2] = (_Float16)v.z; pk.h[3] = (_Float16)v.w;
  ((uint2*)embh)[i] = pk.u;
}

// ---------------------------------------------------------------------------
// Pack gw1[hop][k<128][d] into MFMA B-frag order (f16).
// ---------------------------------------------------------------------------
__global__ void prep_gw1frag_kernel(const float* __restrict__ gw1, _Float16* __restrict__ outf){
  int idx = blockIdx.x*256 + threadIdx.x;     // 2048 = f(32) x lane(64)
  int hop = blockIdx.y;
  int lane = idx & 63, f = idx >> 6;
  int t = f >> 3, n = f & 7;
  int g4 = lane >> 4, col = lane & 15;
  const float* g1 = gw1 + (size_t)hop*129*128;
  size_t base = (size_t)hop*16384 + ((size_t)f*64 + lane)*8;
  #pragma unroll
  for (int j = 0; j < 8; ++j){
    int k = t*32 + g4*8 + j;
    outf[base + j] = (_Float16)g1[(size_t)k*128 + n*16 + col];
  }
}

// ---------------------------------------------------------------------------
// Pack gw3[hop][k<256][d] into MFMA B-frag order (f16).
// ---------------------------------------------------------------------------
__global__ void prep_gw3frag_kernel(const float* __restrict__ gw3, _Float16* __restrict__ outf){
  int idx = blockIdx.x*256 + threadIdx.x;     // 4096 = kt(8) x n(8) x lane(64)
  int hop = blockIdx.y;
  int lane = idx & 63, n = (idx >> 6) & 7, kt = idx >> 9;
  int g4 = lane >> 4, col = lane & 15;
  const float* g3 = gw3 + (size_t)hop*256*128;
  size_t base = (size_t)hop*32768 + ((size_t)(kt*8 + n)*64 + lane)*8;
  #pragma unroll
  for (int j = 0; j < 8; ++j){
    int k = kt*32 + g4*8 + j;
    outf[base + j] = (_Float16)g3[(size_t)k*128 + n*16 + col];
  }
}

// ---------------------------------------------------------------------------
// W'[hop][b] = si_b (x) gw1[hop], f16, frag order; 40 frags (32 + nw block).
// ---------------------------------------------------------------------------
__global__ __launch_bounds__(256) void prep_wprime_kernel(
    const float* __restrict__ gw1, const _Float16* __restrict__ gw1f,
    const float* __restrict__ sum_it, _Float16* __restrict__ wg)
{
  __shared__ float si[128];
  const int b = blockIdx.x, hop = blockIdx.y, tid = threadIdx.x;
  if (tid < 128) si[tid] = sum_it[b*D_ + tid];
  __syncthreads();
  const float* gl = gw1 + (size_t)hop*129*128 + 128*128;   // gw1_last
  _Float16* wb = wg + ((size_t)(hop*128 + b)*40)*512;

  for (int i = 0; i < 10; ++i){
    int slot = i*256 + tid;            // 2560 = 40 frags x 64 lanes
    int f = slot >> 6, l = slot & 63;
    int g4 = l >> 4, col = l & 15;
    union { _Float16 h[8]; uint4 q; } o;
    if (f < 32){
      int t = f >> 3;
      const _Float16* gf = gw1f + (size_t)hop*16384 + ((size_t)f*64 + l)*8;
      int k0 = t*32 + g4*8;
      #pragma unroll
      for (int j = 0; j < 8; ++j)
        o.h[j] = (_Float16)(si[k0+j] * (float)gf[j]);
    } else {
      int n = f - 32, d = n*16 + col;
      #pragma unroll
      for (int j = 0; j < 8; ++j) o.h[j] = (_Float16)0.f;
      if (g4 == 0) o.h[0] = (_Float16)gl[d];
    }
    *(uint4*)(wb + (size_t)slot*8) = o.q;
  }
}

// ---------------------------------------------------------------------------
// GlobalAggregator v9 = v8 + W' staged in LDS once per block.
// R10 audit: W' B-frags were re-read from L2 per PAIR (40KB x 83200 pairs
// = 3.3GB L2 = the dominant stream). Each block serves ONE batch b, so the
// cooperative 40KB load amortizes across 16 pairs; MFMA B-operands become
// ds_read_b128 (contiguous 16B/lane, conflict-free, ~120cy vs L2 200-400cy).
// LDS 62KB/block -> 2 blocks/CU = same 8 waves/CU as the reg-cap (no loss).
// Single-pair loop (R5+R9: 2-pair interleave spills). Stage D block-coop.
// ---------------------------------------------------------------------------
template<bool USE_IDS, bool OUTF32>
__global__ __launch_bounds__(256, 2) void gagg9_kernel(
    const _Float16* __restrict__ embh,
    const int* sv_ids0, const _Float16* sv_vals0,
    const int* nv_ids0, const _Float16* nv_vals0,
    const float* nw0, void* outp0, int M0, int nbpb0, int nblk0,
    const int* sv_ids1, const _Float16* sv_vals1,
    const int* nv_ids1, const _Float16* nv_vals1,
    const float* nw1, void* outp1, int M1, int nbpb1,
    const _Float16* __restrict__ wg,
    const float* __restrict__ gw2, const _Float16* __restrict__ gw3f)
{
  __shared__ _Float16 wlds[40*512];           // 40960 B: W'_b frag image
  __shared__ _Float16 stash[4][12][132];      // 12672 B (wave-private)
  __shared__ _Float16 catl[16][264];          //  8448 B (block-shared)
  const int tid  = threadIdx.x;
  const int wid  = tid >> 6;
  const int lane = tid & 63;
  const int g4   = lane >> 4;
  const int col  = lane & 15;
  const bool colv = col < S_;
  const int sc_  = colv ? col : 0;

  const bool c1 = ((int)blockIdx.x >= nblk0);
  const int  blk = c1 ? (int)blockIdx.x - nblk0 : (int)blockIdx.x;
  const int*       sv_ids  = c1 ? sv_ids1  : sv_ids0;
  const _Float16*  sv_vals = c1 ? sv_vals1 : sv_vals0;
  const int*       nv_ids  = c1 ? nv_ids1  : nv_ids0;
  const _Float16*  nv_vals = c1 ? nv_vals1 : nv_vals0;
  const float*     nw      = c1 ? nw1      : nw0;
  void*            outp    = c1 ? outp1    : outp0;
  const int        M       = c1 ? M1       : M0;
  const int        nbpb    = c1 ? nbpb1    : nbpb0;

  const int b = blk / nbpb;
  const int j = blk - b*nbpb;

  // ---- cooperative W' load: 40960B = 2560 uint4, 10 per thread ----------
  {
    const uint4* src = (const uint4*)(wg + (size_t)b*40*512);
    uint4* dst = (uint4*)wlds;
    #pragma unroll
    for (int i = 0; i < 10; ++i)
      dst[i*256 + tid] = src[i*256 + tid];
  }
  __syncthreads();

  float g2v[8];
  #pragma unroll
  for (int n = 0; n < 8; ++n) g2v[n] = gw2[n*16 + col];

  for (int np = 0; np < 4; ++np){
    const int li0 = j*16 + wid*4 + np;
    const int li  = li0 < M ? li0 : M-1;
    const int p   = b*M + li;

    const _Float16* nvrow = USE_IDS
        ? embh + (size_t)nv_ids[p*S_ + sc_]*D_
        : nv_vals + ((size_t)p*S_ + sc_)*D_;

    f32x4 acc[8];
    #pragma unroll
    for (int n = 0; n < 8; ++n) acc[n] = (f32x4){0.f,0.f,0.f,0.f};

    #pragma unroll
    for (int t = 0; t < 4; ++t){
      half8 af = {0,0,0,0,0,0,0,0};
      if (colv){
        af = *(const half8*)(nvrow + t*32 + g4*8);
        union { half8 v; uint2 q[2]; } ua;
        ua.v = af;
        _Float16* sp = &stash[wid][col][t*32 + g4*8];
        *(uint2*)sp       = ua.q[0];
        *(uint2*)(sp + 4) = ua.q[1];
      }
      #pragma unroll
      for (int n = 0; n < 8; ++n){
        half8 wf = *(const half8*)(wlds + ((size_t)(t*8+n)*64 + lane)*8);
        acc[n] = __builtin_amdgcn_mfma_f32_16x16x32_f16(af, wf, acc[n], 0, 0, 0);
      }
    }
    { // nw K-block (k=128): A col0 = nw[s], B row0 = gw1_last
      half8 af = {0,0,0,0,0,0,0,0};
      if (colv && g4 == 0) af[0] = (_Float16)nw[p*S_ + col];
      #pragma unroll
      for (int n = 0; n < 8; ++n){
        half8 wf = *(const half8*)(wlds + ((size_t)(32+n)*64 + lane)*8);
        acc[n] = __builtin_amdgcn_mfma_f32_16x16x32_f16(af, wf, acc[n], 0, 0, 0);
      }
    }

    // -------- scores -> softmax -> stage C -> catl row ---------------------
    float sc4[4];
    #pragma unroll
    for (int r = 0; r < 4; ++r){
      float pr = 0.f;
      #pragma unroll
      for (int n = 0; n < 8; ++n)
        pr = fmaf(lrelu(acc[n][r]), g2v[n], pr);
      pr += __shfl_xor(pr, 1); pr += __shfl_xor(pr, 2);
      pr += __shfl_xor(pr, 4); pr += __shfl_xor(pr, 8);
      sc4[r] = pr;
    }
    float w[S_];
    {
      float ss[S_];
      #pragma unroll
      for (int grp = 0; grp < 3; ++grp)
        #pragma unroll
        for (int r = 0; r < 4; ++r)
          ss[grp*4 + r] = __shfl(sc4[r], grp*16);
      float m = -1e30f;
      #pragma unroll
      for (int s = 0; s < S_; ++s) m = fmaxf(m, ss[s]);
      float sum = 0.f;
      #pragma unroll
      for (int s = 0; s < S_; ++s){ ss[s] = expf(ss[s]-m); sum += ss[s]; }
      float inv = 1.f/sum;
      #pragma unroll
      for (int s = 0; s < S_; ++s) w[s] = ss[s]*inv;
    }
    float aggx = 0.f, aggy = 0.f;
    #pragma unroll
    for (int s = 0; s < S_; ++s){
      union { unsigned q; _Float16 h[2]; } v;
      v.q = *(const unsigned*)&stash[wid][s][2*lane];
      aggx = fmaf(w[s], (float)v.h[0], aggx);
      aggy = fmaf(w[s], (float)v.h[1], aggy);
    }
    const _Float16* svrow = USE_IDS ? embh + (size_t)sv_ids[p]*D_
                                    : sv_vals + (size_t)p*D_;
    const int row = wid*4 + np;
    *(unsigned*)&catl[row][2*lane] = *(const unsigned*)(svrow + 2*lane);
    union { unsigned q; _Float16 h[2]; } pk;
    pk.h[0] = (_Float16)aggx; pk.h[1] = (_Float16)aggy;
    *(unsigned*)&catl[row][D_ + 2*lane] = pk.q;
  }

  __syncthreads();   // catl is block-shared

  // -------- stage D: [16x256]@[256x128] f16 MFMA, wave owns 2 n-frags -----
  const half8* g3fp = (const half8*)gw3f;
  f32x4 dacc[2];
  dacc[0] = (f32x4){0.f,0.f,0.f,0.f};
  dacc[1] = (f32x4){0.f,0.f,0.f,0.f};

  #pragma unroll
  for (int kt = 0; kt < 8; ++kt){
    half8 afr = *(const half8*)&catl[col][kt*32 + g4*8];
    #pragma unroll
    for (int nn = 0; nn < 2; ++nn){
      int n = wid*2 + nn;
      dacc[nn] = __builtin_amdgcn_mfma_f32_16x16x32_f16(afr, g3fp[(kt*8+n)*64 + lane], dacc[nn], 0, 0, 0);
    }
  }

  #pragma unroll
  for (int nn = 0; nn < 2; ++nn){
    int n = wid*2 + nn;
    #pragma unroll
    for (int r = 0; r < 4; ++r){
      int li = j*16 + g4*4 + r;
      if (li < M){
        size_t off = (size_t)(b*M + li)*D_ + n*16 + col;
        float v = fmaxf(dacc[nn][r], 0.f);
        if (OUTF32) ((float*)outp)[off] = v;
        else        ((_Float16*)outp)[off] = (_Float16)v;
      }
    }
  }
}

// ---------------------------------------------------------------------------
// output = h_local + s_global
// ---------------------------------------------------------------------------
__global__ void final_add_kernel(float* __restrict__ dout){
  int i = blockIdx.x*blockDim.x + threadIdx.x;
  const int n4 = (B_*L_*D_)/4;
  if (i < n4){
    float4* o = (float4*)dout;
    const float4* s = (const float4*)(dout + B_*L_*D_);
    float4 a = o[i], b = s[i];
    a.x += b.x; a.y += b.y; a.z += b.z; a.w += b.w;
    o[i] = a;
  }
}

extern "C" void kernel_launch(void* const* d_in, const int* in_sizes, int n_in,
                              void* d_out, int out_size, void* d_ws, size_t ws_size,
                              hipStream_t stream)
{
  const int*   inputs  = (const int*)  d_in[0];
  const int*   adj     = (const int*)  d_in[1];
  const int*   mask    = (const int*)  d_in[2];
  const int*   item    = (const int*)  d_in[3];
  const float* emb     = (const float*)d_in[4];
  const int*   adj_all = (const int*)  d_in[5];
  const float* num_w   = (const float*)d_in[6];
  const float* a0      = (const float*)d_in[7];
  const float* a1      = (const float*)d_in[8];
  const float* a2      = (const float*)d_in[9];
  const float* a3      = (const float*)d_in[10];
  const float* gw1     = (const float*)d_in[11];  // [2][129][128]
  const float* gw2     = (const float*)d_in[12];  // [2][128]
  const float* gw3     = (const float*)d_in[13];  // [2][256][128]

  float* out     = (float*)d_out;
  float* hlocal  = out;
  float* sglobal = out + B_*L_*D_;

  char* ws = (char*)d_ws;
  size_t off = 0;
  auto alloc = [&](size_t bytes)->char*{
    char* pp = ws + off; off += (bytes + 255) & ~(size_t)255; return pp;
  };
  float*    sum_it = (float*)alloc((size_t)B_*D_*sizeof(float));
  int*      n1     = (int*)  alloc((size_t)B_*L_*S_*sizeof(int));
  float*    w0     = (float*)alloc((size_t)B_*L_*S_*sizeof(float));
  int*      n2     = (int*)  alloc((size_t)B_*L_*S_*S_*sizeof(int));
  float*    w1     = (float*)alloc((size_t)B_*L_*S_*S_*sizeof(float));
  _Float16* out0h  = (_Float16*)alloc((size_t)B_*L_*D_*sizeof(_Float16));
  _Float16* out1h  = (_Float16*)alloc((size_t)B_*L_*S_*D_*sizeof(_Float16));
  _Float16* embh   = (_Float16*)alloc((size_t)100000*D_*sizeof(_Float16));
  _Float16* gw1f   = (_Float16*)alloc((size_t)2*16384*sizeof(_Float16));
  _Float16* gw3f   = (_Float16*)alloc((size_t)2*32768*sizeof(_Float16));
  _Float16* wgAll  = (_Float16*)alloc((size_t)2*128*40*512*sizeof(_Float16)); // 10.5MB

  emb2f16_kernel<<<(100000*D_/4 + 255)/256, 256, 0, stream>>>(emb, embh, 100000*D_/4);
  prep_gw1frag_kernel<<<dim3(8,2), 256, 0, stream>>>(gw1, gw1f);
  prep_gw3frag_kernel<<<dim3(16,2), 256, 0, stream>>>(gw3, gw3f);
  local_agg_kernel<<<dim3(B_,4), 256, 0, stream>>>(inputs, adj, emb, a0, a1, a2, a3, hlocal);
  sum_item_kernel<<<B_, 128, 0, stream>>>(item, mask, emb, sum_it);
  build_nbr_kernel<<<(B_*L_*S_ + 255)/256, 256, 0, stream>>>(inputs, B_*L_*S_, adj_all, num_w, n1, w0);
  build_nbr_kernel<<<(B_*L_*S_*S_ + 255)/256, 256, 0, stream>>>(n1, B_*L_*S_*S_, adj_all, num_w, n2, w1);
  prep_wprime_kernel<<<dim3(B_,2), 256, 0, stream>>>(gw1, gw1f, sum_it, wgAll);

  // Fused hop0: cfg0 = pass A (ids, emb -> out0h, M=50, nbpb=4, 512 blocks)
  //             cfg1 = pass B (ids, emb -> out1h, M=600, nbpb=38, 4864 blocks)
  {
    const int nblkA = B_*4;        // 512
    const int nblkB = B_*38;       // 4864
    gagg9_kernel<true,false><<<nblkA + nblkB, 256, 0, stream>>>(
        embh,
        inputs, nullptr, n1, nullptr, w0, out0h, L_,   4, nblkA,
        n1,     nullptr, n2, nullptr, w1, out1h, L_*S_, 38,
        wgAll, gw2, gw3f);
  }
  // hop1 (pass C): vals = out0h/out1h, hop1 W', f32 out -> sglobal
  {
    const int nblkC = B_*4;        // 512
    gagg9_kernel<false,true><<<nblkC, 256, 0, stream>>>(
        embh,
        nullptr, out0h, nullptr, out1h, w0, sglobal, L_, 4, nblkC,
        nullptr, out0h, nullptr, out1h, w0, sglobal, L_, 4,
        wgAll + (size_t)128*40*512, gw2 + 128, gw3f + 32768);
  }

  final_add_kernel<<<((B_*L_*D_/4) + 255)/256, 256, 0, stream>>>(out);
}

// Round 12
// 242.844 us; speedup vs baseline: 1.8697x; 1.0567x over previous
//
#include <hip/hip_runtime.h>
#include <hip/hip_bf16.h>
#include <math.h>

#define B_ 128
#define L_ 50
#define D_ 128
#define S_ 12
#define NEG_INF_ -9e15f

typedef __attribute__((ext_vector_type(8))) _Float16 half8;
typedef __attribute__((ext_vector_type(4))) float f32x4;

static __device__ __forceinline__ float lrelu(float x){ return fmaxf(x, 0.2f*x); }
static __device__ __forceinline__ float fexp(float x){ return __expf(x); }        // v_exp_f32 path
static __device__ __forceinline__ float frcp(float x){ return __builtin_amdgcn_rcpf(x); }

// ---------------------------------------------------------------------------
// Local aggregator: 4-edge-type GAT. Grid (B, 4).
// ---------------------------------------------------------------------------
__global__ __launch_bounds__(256) void local_agg_kernel(
    const int* __restrict__ inputs, const int* __restrict__ adj,
    const float* __restrict__ emb,
    const float* __restrict__ a0, const float* __restrict__ a1,
    const float* __restrict__ a2, const float* __restrict__ a3,
    float* __restrict__ hlocal_out)
{
  __shared__ float hs[L_][129];
  __shared__ float alds[4][129];
  __shared__ float att[13][51];
  const int b = blockIdx.x, tid = threadIdx.x;
  const int r0 = blockIdx.y * 13;
  const int nr = (L_ - r0) < 13 ? (L_ - r0) : 13;

  if (tid < 128){
    alds[0][tid] = a0[tid]; alds[1][tid] = a1[tid];
    alds[2][tid] = a2[tid]; alds[3][tid] = a3[tid];
  }
  for (int i = tid; i < L_*D_; i += 256){
    int r = i >> 7, d = i & 127;
    hs[r][d] = emb[(size_t)inputs[b*L_ + r]*D_ + d];
  }
  __syncthreads();

  for (int pth = tid; pth < nr*L_; pth += 256){
    int i = pth / L_, j = pth % L_;
    int at = adj[b*L_*L_ + (r0+i)*L_ + j];
    float lg = NEG_INF_;
    if (at >= 1 && at <= 4){
      const float* av = alds[at-1];
      float acc = 0.f;
      #pragma unroll 4
      for (int d = 0; d < D_; ++d) acc = fmaf(hs[r0+i][d]*hs[j][d], av[d], acc);
      lg = lrelu(acc);
    }
    att[i][j] = lg;
  }
  __syncthreads();

  if (tid < nr){
    float m = -1e30f;
    for (int j = 0; j < L_; ++j) m = fmaxf(m, att[tid][j]);
    float sum = 0.f;
    for (int j = 0; j < L_; ++j){ float e = fexp(att[tid][j]-m); att[tid][j] = e; sum += e; }
    float inv = frcp(sum);
    for (int j = 0; j < L_; ++j) att[tid][j] *= inv;
  }
  __syncthreads();

  for (int i2 = tid; i2 < nr*D_; i2 += 256){
    int r = i2 >> 7, d = i2 & 127;
    float acc = 0.f;
    #pragma unroll 5
    for (int j = 0; j < L_; ++j) acc = fmaf(att[r][j], hs[j][d], acc);
    hlocal_out[(size_t)b*L_*D_ + (size_t)(r0+r)*D_ + d] = acc;
  }
}

// ---------------------------------------------------------------------------
// Session mean
// ---------------------------------------------------------------------------
__global__ __launch_bounds__(128) void sum_item_kernel(
    const int* __restrict__ item, const int* __restrict__ mask,
    const float* __restrict__ emb, float* __restrict__ sum_it)
{
  const int b = blockIdx.x, d = threadIdx.x;
  float acc = 0.f, cnt = 0.f;
  for (int l = 0; l < L_; ++l){
    float mf = (float)mask[b*L_ + l];
    acc = fmaf(mf, emb[(size_t)item[b*L_+l]*D_ + d], acc);
    cnt += mf;
  }
  sum_it[b*D_ + d] = acc / cnt;
}

// ---------------------------------------------------------------------------
// Neighbor expansion
// ---------------------------------------------------------------------------
__global__ void build_nbr_kernel(const int* __restrict__ src_ids, int n,
                                 const int* __restrict__ adj_all,
                                 const float* __restrict__ num_w,
                                 int* __restrict__ out_ids, float* __restrict__ out_w)
{
  int t = blockIdx.x*blockDim.x + threadIdx.x;
  if (t >= n) return;
  int parent = src_ids[t / S_];
  int s = t % S_;
  out_ids[t] = adj_all[(size_t)parent*S_ + s];
  out_w[t]   = num_w[(size_t)parent*S_ + s];
}

// ---------------------------------------------------------------------------
// emb f32 -> f16 table
// ---------------------------------------------------------------------------
__global__ void emb2f16_kernel(const float* __restrict__ emb,
                               _Float16* __restrict__ embh, int n4)
{
  int i = blockIdx.x*256 + threadIdx.x;
  if (i >= n4) return;
  float4 v = ((const float4*)emb)[i];
  union { _Float16 h[4]; uint2 u; } pk;
  pk.h[0] = (_Float16)v.x; pk.h[1] = (_Float16)v.y;
  pk.h[2] = (_Float16)v.z; pk.h[3] = (_Float16)v.w;
  ((uint2*)embh)[i] = pk.u;
}

// ---------------------------------------------------------------------------
// Pack gw1[hop][k<128][d] into MFMA B-frag order (f16).
// ---------------------------------------------------------------------------
__global__ void prep_gw1frag_kernel(const float* __restrict__ gw1, _Float16* __restrict__ outf){
  int idx = blockIdx.x*256 + threadIdx.x;     // 2048 = f(32) x lane(64)
  int hop = blockIdx.y;
  int lane = idx & 63, f = idx >> 6;
  int t = f >> 3, n = f & 7;
  int g4 = lane >> 4, col = lane & 15;
  const float* g1 = gw1 + (size_t)hop*129*128;
  size_t base = (size_t)hop*16384 + ((size_t)f*64 + lane)*8;
  #pragma unroll
  for (int j = 0; j < 8; ++j){
    int k = t*32 + g4*8 + j;
    outf[base + j] = (_Float16)g1[(size_t)k*128 + n*16 + col];
  }
}

// ---------------------------------------------------------------------------
// Pack gw3[hop][k<256][d] into MFMA B-frag order (f16).
// ---------------------------------------------------------------------------
__global__ void prep_gw3frag_kernel(const float* __restrict__ gw3, _Float16* __restrict__ outf){
  int idx = blockIdx.x*256 + threadIdx.x;     // 4096 = kt(8) x n(8) x lane(64)
  int hop = blockIdx.y;
  int lane = idx & 63, n = (idx >> 6) & 7, kt = idx >> 9;
  int g4 = lane >> 4, col = lane & 15;
  const float* g3 = gw3 + (size_t)hop*256*128;
  size_t base = (size_t)hop*32768 + ((size_t)(kt*8 + n)*64 + lane)*8;
  #pragma unroll
  for (int j = 0; j < 8; ++j){
    int k = kt*32 + g4*8 + j;
    outf[base + j] = (_Float16)g3[(size_t)k*128 + n*16 + col];
  }
}

// ---------------------------------------------------------------------------
// W'[hop][b] = si_b (x) gw1[hop], f16, frag order; 40 frags (32 + nw block).
// ---------------------------------------------------------------------------
__global__ __launch_bounds__(256) void prep_wprime_kernel(
    const float* __restrict__ gw1, const _Float16* __restrict__ gw1f,
    const float* __restrict__ sum_it, _Float16* __restrict__ wg)
{
  __shared__ float si[128];
  const int b = blockIdx.x, hop = blockIdx.y, tid = threadIdx.x;
  if (tid < 128) si[tid] = sum_it[b*D_ + tid];
  __syncthreads();
  const float* gl = gw1 + (size_t)hop*129*128 + 128*128;   // gw1_last
  _Float16* wb = wg + ((size_t)(hop*128 + b)*40)*512;

  for (int i = 0; i < 10; ++i){
    int slot = i*256 + tid;            // 2560 = 40 frags x 64 lanes
    int f = slot >> 6, l = slot & 63;
    int g4 = l >> 4, col = l & 15;
    union { _Float16 h[8]; uint4 q; } o;
    if (f < 32){
      int t = f >> 3;
      const _Float16* gf = gw1f + (size_t)hop*16384 + ((size_t)f*64 + l)*8;
      int k0 = t*32 + g4*8;
      #pragma unroll
      for (int j = 0; j < 8; ++j)
        o.h[j] = (_Float16)(si[k0+j] * (float)gf[j]);
    } else {
      int n = f - 32, d = n*16 + col;
      #pragma unroll
      for (int j = 0; j < 8; ++j) o.h[j] = (_Float16)0.f;
      if (g4 == 0) o.h[0] = (_Float16)gl[d];
    }
    *(uint4*)(wb + (size_t)slot*8) = o.q;
  }
}

// ---------------------------------------------------------------------------
// GlobalAggregator v10 = v9 + fast transcendentals in the softmax tail.
// R11 cycle model: chain-latency-bound; per-pair VALU ~540cy of which ~216
// was 12x expf LIBCALLS (~18 instrs each). __expf = v_exp_f32 (2 instrs),
// rcp for 1/sum, 4-deep tree max. Everything else identical to v9
// (W' in LDS; single-pair loop -- R5/R9: interleave spills; stage D coop).
// ---------------------------------------------------------------------------
template<bool USE_IDS, bool OUTF32>
__global__ __launch_bounds__(256, 2) void gagg10_kernel(
    const _Float16* __restrict__ embh,
    const int* sv_ids0, const _Float16* sv_vals0,
    const int* nv_ids0, const _Float16* nv_vals0,
    const float* nw0, void* outp0, int M0, int nbpb0, int nblk0,
    const int* sv_ids1, const _Float16* sv_vals1,
    const int* nv_ids1, const _Float16* nv_vals1,
    const float* nw1, void* outp1, int M1, int nbpb1,
    const _Float16* __restrict__ wg,
    const float* __restrict__ gw2, const _Float16* __restrict__ gw3f)
{
  __shared__ _Float16 wlds[40*512];           // 40960 B: W'_b frag image
  __shared__ _Float16 stash[4][12][132];      // 12672 B (wave-private)
  __shared__ _Float16 catl[16][264];          //  8448 B (block-shared)
  const int tid  = threadIdx.x;
  const int wid  = tid >> 6;
  const int lane = tid & 63;
  const int g4   = lane >> 4;
  const int col  = lane & 15;
  const bool colv = col < S_;
  const int sc_  = colv ? col : 0;

  const bool c1 = ((int)blockIdx.x >= nblk0);
  const int  blk = c1 ? (int)blockIdx.x - nblk0 : (int)blockIdx.x;
  const int*       sv_ids  = c1 ? sv_ids1  : sv_ids0;
  const _Float16*  sv_vals = c1 ? sv_vals1 : sv_vals0;
  const int*       nv_ids  = c1 ? nv_ids1  : nv_ids0;
  const _Float16*  nv_vals = c1 ? nv_vals1 : nv_vals0;
  const float*     nw      = c1 ? nw1      : nw0;
  void*            outp    = c1 ? outp1    : outp0;
  const int        M       = c1 ? M1       : M0;
  const int        nbpb    = c1 ? nbpb1    : nbpb0;

  const int b = blk / nbpb;
  const int j = blk - b*nbpb;

  // ---- cooperative W' load: 40960B = 2560 uint4, 10 per thread ----------
  {
    const uint4* src = (const uint4*)(wg + (size_t)b*40*512);
    uint4* dst = (uint4*)wlds;
    #pragma unroll
    for (int i = 0; i < 10; ++i)
      dst[i*256 + tid] = src[i*256 + tid];
  }
  __syncthreads();

  float g2v[8];
  #pragma unroll
  for (int n = 0; n < 8; ++n) g2v[n] = gw2[n*16 + col];

  for (int np = 0; np < 4; ++np){
    const int li0 = j*16 + wid*4 + np;
    const int li  = li0 < M ? li0 : M-1;
    const int p   = b*M + li;

    const _Float16* nvrow = USE_IDS
        ? embh + (size_t)nv_ids[p*S_ + sc_]*D_
        : nv_vals + ((size_t)p*S_ + sc_)*D_;

    f32x4 acc[8];
    #pragma unroll
    for (int n = 0; n < 8; ++n) acc[n] = (f32x4){0.f,0.f,0.f,0.f};

    #pragma unroll
    for (int t = 0; t < 4; ++t){
      half8 af = {0,0,0,0,0,0,0,0};
      if (colv){
        af = *(const half8*)(nvrow + t*32 + g4*8);
        union { half8 v; uint2 q[2]; } ua;
        ua.v = af;
        _Float16* sp = &stash[wid][col][t*32 + g4*8];
        *(uint2*)sp       = ua.q[0];
        *(uint2*)(sp + 4) = ua.q[1];
      }
      #pragma unroll
      for (int n = 0; n < 8; ++n){
        half8 wf = *(const half8*)(wlds + ((size_t)(t*8+n)*64 + lane)*8);
        acc[n] = __builtin_amdgcn_mfma_f32_16x16x32_f16(af, wf, acc[n], 0, 0, 0);
      }
    }
    { // nw K-block (k=128): A col0 = nw[s], B row0 = gw1_last
      half8 af = {0,0,0,0,0,0,0,0};
      if (colv && g4 == 0) af[0] = (_Float16)nw[p*S_ + col];
      #pragma unroll
      for (int n = 0; n < 8; ++n){
        half8 wf = *(const half8*)(wlds + ((size_t)(32+n)*64 + lane)*8);
        acc[n] = __builtin_amdgcn_mfma_f32_16x16x32_f16(af, wf, acc[n], 0, 0, 0);
      }
    }

    // -------- scores -> softmax (fast-exp) -> stage C -> catl row ----------
    float sc4[4];
    #pragma unroll
    for (int r = 0; r < 4; ++r){
      float pr = 0.f;
      #pragma unroll
      for (int n = 0; n < 8; ++n)
        pr = fmaf(lrelu(acc[n][r]), g2v[n], pr);
      pr += __shfl_xor(pr, 1); pr += __shfl_xor(pr, 2);
      pr += __shfl_xor(pr, 4); pr += __shfl_xor(pr, 8);
      sc4[r] = pr;
    }
    float w[S_];
    {
      float ss[S_];
      #pragma unroll
      for (int grp = 0; grp < 3; ++grp)
        #pragma unroll
        for (int r = 0; r < 4; ++r)
          ss[grp*4 + r] = __shfl(sc4[r], grp*16);
      // 4-deep tree max over 12
      float m01 = fmaxf(ss[0], ss[1]),  m23 = fmaxf(ss[2], ss[3]);
      float m45 = fmaxf(ss[4], ss[5]),  m67 = fmaxf(ss[6], ss[7]);
      float m89 = fmaxf(ss[8], ss[9]),  mab = fmaxf(ss[10], ss[11]);
      float m = fmaxf(fmaxf(fmaxf(m01, m23), fmaxf(m45, m67)), fmaxf(m89, mab));
      float sum = 0.f;
      #pragma unroll
      for (int s = 0; s < S_; ++s){ ss[s] = fexp(ss[s]-m); sum += ss[s]; }
      float inv = frcp(sum);
      #pragma unroll
      for (int s = 0; s < S_; ++s) w[s] = ss[s]*inv;
    }
    float aggx = 0.f, aggy = 0.f;
    #pragma unroll
    for (int s = 0; s < S_; ++s){
      union { unsigned q; _Float16 h[2]; } v;
      v.q = *(const unsigned*)&stash[wid][s][2*lane];
      aggx = fmaf(w[s], (float)v.h[0], aggx);
      aggy = fmaf(w[s], (float)v.h[1], aggy);
    }
    const _Float16* svrow = USE_IDS ? embh + (size_t)sv_ids[p]*D_
                                    : sv_vals + (size_t)p*D_;
    const int row = wid*4 + np;
    *(unsigned*)&catl[row][2*lane] = *(const unsigned*)(svrow + 2*lane);
    union { unsigned q; _Float16 h[2]; } pk;
    pk.h[0] = (_Float16)aggx; pk.h[1] = (_Float16)aggy;
    *(unsigned*)&catl[row][D_ + 2*lane] = pk.q;
  }

  __syncthreads();   // catl is block-shared

  // -------- stage D: [16x256]@[256x128] f16 MFMA, wave owns 2 n-frags -----
  const half8* g3fp = (const half8*)gw3f;
  f32x4 dacc[2];
  dacc[0] = (f32x4){0.f,0.f,0.f,0.f};
  dacc[1] = (f32x4){0.f,0.f,0.f,0.f};

  #pragma unroll
  for (int kt = 0; kt < 8; ++kt){
    half8 afr = *(const half8*)&catl[col][kt*32 + g4*8];
    #pragma unroll
    for (int nn = 0; nn < 2; ++nn){
      int n = wid*2 + nn;
      dacc[nn] = __builtin_amdgcn_mfma_f32_16x16x32_f16(afr, g3fp[(kt*8+n)*64 + lane], dacc[nn], 0, 0, 0);
    }
  }

  #pragma unroll
  for (int nn = 0; nn < 2; ++nn){
    int n = wid*2 + nn;
    #pragma unroll
    for (int r = 0; r < 4; ++r){
      int li = j*16 + g4*4 + r;
      if (li < M){
        size_t off = (size_t)(b*M + li)*D_ + n*16 + col;
        float v = fmaxf(dacc[nn][r], 0.f);
        if (OUTF32) ((float*)outp)[off] = v;
        else        ((_Float16*)outp)[off] = (_Float16)v;
      }
    }
  }
}

// ---------------------------------------------------------------------------
// output = h_local + s_global
// ---------------------------------------------------------------------------
__global__ void final_add_kernel(float* __restrict__ dout){
  int i = blockIdx.x*blockDim.x + threadIdx.x;
  const int n4 = (B_*L_*D_)/4;
  if (i < n4){
    float4* o = (float4*)dout;
    const float4* s = (const float4*)(dout + B_*L_*D_);
    float4 a = o[i], b = s[i];
    a.x += b.x; a.y += b.y; a.z += b.z; a.w += b.w;
    o[i] = a;
  }
}

extern "C" void kernel_launch(void* const* d_in, const int* in_sizes, int n_in,
                              void* d_out, int out_size, void* d_ws, size_t ws_size,
                              hipStream_t stream)
{
  const int*   inputs  = (const int*)  d_in[0];
  const int*   adj     = (const int*)  d_in[1];
  const int*   mask    = (const int*)  d_in[2];
  const int*   item    = (const int*)  d_in[3];
  const float* emb     = (const float*)d_in[4];
  const int*   adj_all = (const int*)  d_in[5];
  const float* num_w   = (const float*)d_in[6];
  const float* a0      = (const float*)d_in[7];
  const float* a1      = (const float*)d_in[8];
  const float* a2      = (const float*)d_in[9];
  const float* a3      = (const float*)d_in[10];
  const float* gw1     = (const float*)d_in[11];  // [2][129][128]
  const float* gw2     = (const float*)d_in[12];  // [2][128]
  const float* gw3     = (const float*)d_in[13];  // [2][256][128]

  float* out     = (float*)d_out;
  float* hlocal  = out;
  float* sglobal = out + B_*L_*D_;

  char* ws = (char*)d_ws;
  size_t off = 0;
  auto alloc = [&](size_t bytes)->char*{
    char* pp = ws + off; off += (bytes + 255) & ~(size_t)255; return pp;
  };
  float*    sum_it = (float*)alloc((size_t)B_*D_*sizeof(float));
  int*      n1     = (int*)  alloc((size_t)B_*L_*S_*sizeof(int));
  float*    w0     = (float*)alloc((size_t)B_*L_*S_*sizeof(float));
  int*      n2     = (int*)  alloc((size_t)B_*L_*S_*S_*sizeof(int));
  float*    w1     = (float*)alloc((size_t)B_*L_*S_*S_*sizeof(float));
  _Float16* out0h  = (_Float16*)alloc((size_t)B_*L_*D_*sizeof(_Float16));
  _Float16* out1h  = (_Float16*)alloc((size_t)B_*L_*S_*D_*sizeof(_Float16));
  _Float16* embh   = (_Float16*)alloc((size_t)100000*D_*sizeof(_Float16));
  _Float16* gw1f   = (_Float16*)alloc((size_t)2*16384*sizeof(_Float16));
  _Float16* gw3f   = (_Float16*)alloc((size_t)2*32768*sizeof(_Float16));
  _Float16* wgAll  = (_Float16*)alloc((size_t)2*128*40*512*sizeof(_Float16)); // 10.5MB

  emb2f16_kernel<<<(100000*D_/4 + 255)/256, 256, 0, stream>>>(emb, embh, 100000*D_/4);
  prep_gw1frag_kernel<<<dim3(8,2), 256, 0, stream>>>(gw1, gw1f);
  prep_gw3frag_kernel<<<dim3(16,2), 256, 0, stream>>>(gw3, gw3f);
  local_agg_kernel<<<dim3(B_,4), 256, 0, stream>>>(inputs, adj, emb, a0, a1, a2, a3, hlocal);
  sum_item_kernel<<<B_, 128, 0, stream>>>(item, mask, emb, sum_it);
  build_nbr_kernel<<<(B_*L_*S_ + 255)/256, 256, 0, stream>>>(inputs, B_*L_*S_, adj_all, num_w, n1, w0);
  build_nbr_kernel<<<(B_*L_*S_*S_ + 255)/256, 256, 0, stream>>>(n1, B_*L_*S_*S_, adj_all, num_w, n2, w1);
  prep_wprime_kernel<<<dim3(B_,2), 256, 0, stream>>>(gw1, gw1f, sum_it, wgAll);

  // Fused hop0: cfg0 = pass A (ids, emb -> out0h, M=50, nbpb=4, 512 blocks)
  //             cfg1 = pass B (ids, emb -> out1h, M=600, nbpb=38, 4864 blocks)
  {
    const int nblkA = B_*4;        // 512
    const int nblkB = B_*38;       // 4864
    gagg10_kernel<true,false><<<nblkA + nblkB, 256, 0, stream>>>(
        embh,
        inputs, nullptr, n1, nullptr, w0, out0h, L_,   4, nblkA,
        n1,     nullptr, n2, nullptr, w1, out1h, L_*S_, 38,
        wgAll, gw2, gw3f);
  }
  // hop1 (pass C): vals = out0h/out1h, hop1 W', f32 out -> sglobal
  {
    const int nblkC = B_*4;        // 512
    gagg10_kernel<false,true><<<nblkC, 256, 0, stream>>>(
        embh,
        nullptr, out0h, nullptr, out1h, w0, sglobal, L_, 4, nblkC,
        nullptr, out0h, nullptr, out1h, w0, sglobal, L_, 4,
        wgAll + (size_t)128*40*512, gw2 + 128, gw3f + 32768);
  }

  final_add_kernel<<<((B_*L_*D_/4) + 255)/256, 256, 0, stream>>>(out);
}

// Round 13
// 235.245 us; speedup vs baseline: 1.9301x; 1.0323x over previous
//
#include <hip/hip_runtime.h>
#include <hip/hip_bf16.h>
#include <math.h>

#define B_ 128
#define L_ 50
#define D_ 128
#define S_ 12
#define NEG_INF_ -9e15f

typedef __attribute__((ext_vector_type(8))) _Float16 half8;
typedef __attribute__((ext_vector_type(4))) float f32x4;

static __device__ __forceinline__ float lrelu(float x){ return fmaxf(x, 0.2f*x); }
static __device__ __forceinline__ float fexp(float x){ return __expf(x); }
static __device__ __forceinline__ float frcp(float x){ return __builtin_amdgcn_rcpf(x); }

// ---------------------------------------------------------------------------
// Local aggregator: 4-edge-type GAT. Grid (B, 4).
// ---------------------------------------------------------------------------
__global__ __launch_bounds__(256) void local_agg_kernel(
    const int* __restrict__ inputs, const int* __restrict__ adj,
    const float* __restrict__ emb,
    const float* __restrict__ a0, const float* __restrict__ a1,
    const float* __restrict__ a2, const float* __restrict__ a3,
    float* __restrict__ hlocal_out)
{
  __shared__ float hs[L_][129];
  __shared__ float alds[4][129];
  __shared__ float att[13][51];
  const int b = blockIdx.x, tid = threadIdx.x;
  const int r0 = blockIdx.y * 13;
  const int nr = (L_ - r0) < 13 ? (L_ - r0) : 13;

  if (tid < 128){
    alds[0][tid] = a0[tid]; alds[1][tid] = a1[tid];
    alds[2][tid] = a2[tid]; alds[3][tid] = a3[tid];
  }
  for (int i = tid; i < L_*D_; i += 256){
    int r = i >> 7, d = i & 127;
    hs[r][d] = emb[(size_t)inputs[b*L_ + r]*D_ + d];
  }
  __syncthreads();

  for (int pth = tid; pth < nr*L_; pth += 256){
    int i = pth / L_, j = pth % L_;
    int at = adj[b*L_*L_ + (r0+i)*L_ + j];
    float lg = NEG_INF_;
    if (at >= 1 && at <= 4){
      const float* av = alds[at-1];
      float acc = 0.f;
      #pragma unroll 4
      for (int d = 0; d < D_; ++d) acc = fmaf(hs[r0+i][d]*hs[j][d], av[d], acc);
      lg = lrelu(acc);
    }
    att[i][j] = lg;
  }
  __syncthreads();

  if (tid < nr){
    float m = -1e30f;
    for (int j = 0; j < L_; ++j) m = fmaxf(m, att[tid][j]);
    float sum = 0.f;
    for (int j = 0; j < L_; ++j){ float e = fexp(att[tid][j]-m); att[tid][j] = e; sum += e; }
    float inv = frcp(sum);
    for (int j = 0; j < L_; ++j) att[tid][j] *= inv;
  }
  __syncthreads();

  for (int i2 = tid; i2 < nr*D_; i2 += 256){
    int r = i2 >> 7, d = i2 & 127;
    float acc = 0.f;
    #pragma unroll 5
    for (int j = 0; j < L_; ++j) acc = fmaf(att[r][j], hs[j][d], acc);
    hlocal_out[(size_t)b*L_*D_ + (size_t)(r0+r)*D_ + d] = acc;
  }
}

// ---------------------------------------------------------------------------
// Session mean
// ---------------------------------------------------------------------------
__global__ __launch_bounds__(128) void sum_item_kernel(
    const int* __restrict__ item, const int* __restrict__ mask,
    const float* __restrict__ emb, float* __restrict__ sum_it)
{
  const int b = blockIdx.x, d = threadIdx.x;
  float acc = 0.f, cnt = 0.f;
  for (int l = 0; l < L_; ++l){
    float mf = (float)mask[b*L_ + l];
    acc = fmaf(mf, emb[(size_t)item[b*L_+l]*D_ + d], acc);
    cnt += mf;
  }
  sum_it[b*D_ + d] = acc / cnt;
}

// ---------------------------------------------------------------------------
// Neighbor expansion
// ---------------------------------------------------------------------------
__global__ void build_nbr_kernel(const int* __restrict__ src_ids, int n,
                                 const int* __restrict__ adj_all,
                                 const float* __restrict__ num_w,
                                 int* __restrict__ out_ids, float* __restrict__ out_w)
{
  int t = blockIdx.x*blockDim.x + threadIdx.x;
  if (t >= n) return;
  int parent = src_ids[t / S_];
  int s = t % S_;
  out_ids[t] = adj_all[(size_t)parent*S_ + s];
  out_w[t]   = num_w[(size_t)parent*S_ + s];
}

// ---------------------------------------------------------------------------
// emb f32 -> f16 table
// ---------------------------------------------------------------------------
__global__ void emb2f16_kernel(const float* __restrict__ emb,
                               _Float16* __restrict__ embh, int n4)
{
  int i = blockIdx.x*256 + threadIdx.x;
  if (i >= n4) return;
  float4 v = ((const float4*)emb)[i];
  union { _Float16 h[4]; uint2 u; } pk;
  pk.h[0] = (_Float16)v.x; pk.h[1] = (_Float16)v.y;
  pk.h[2] = (_Float16)v.z; pk.h[3] = (_Float16)v.w;
  ((uint2*)embh)[i] = pk.u;
}

// ---------------------------------------------------------------------------
// Pack gw1[hop][k<128][d] into MFMA B-frag order (f16).
// ---------------------------------------------------------------------------
__global__ void prep_gw1frag_kernel(const float* __restrict__ gw1, _Float16* __restrict__ outf){
  int idx = blockIdx.x*256 + threadIdx.x;     // 2048 = f(32) x lane(64)
  int hop = blockIdx.y;
  int lane = idx & 63, f = idx >> 6;
  int t = f >> 3, n = f & 7;
  int g4 = lane >> 4, col = lane & 15;
  const float* g1 = gw1 + (size_t)hop*129*128;
  size_t base = (size_t)hop*16384 + ((size_t)f*64 + lane)*8;
  #pragma unroll
  for (int j = 0; j < 8; ++j){
    int k = t*32 + g4*8 + j;
    outf[base + j] = (_Float16)g1[(size_t)k*128 + n*16 + col];
  }
}

// ---------------------------------------------------------------------------
// Pack gw3[hop][k<256][d] into MFMA B-frag order (f16).
// ---------------------------------------------------------------------------
__global__ void prep_gw3frag_kernel(const float* __restrict__ gw3, _Float16* __restrict__ outf){
  int idx = blockIdx.x*256 + threadIdx.x;     // 4096 = kt(8) x n(8) x lane(64)
  int hop = blockIdx.y;
  int lane = idx & 63, n = (idx >> 6) & 7, kt = idx >> 9;
  int g4 = lane >> 4, col = lane & 15;
  const float* g3 = gw3 + (size_t)hop*256*128;
  size_t base = (size_t)hop*32768 + ((size_t)(kt*8 + n)*64 + lane)*8;
  #pragma unroll
  for (int j = 0; j < 8; ++j){
    int k = kt*32 + g4*8 + j;
    outf[base + j] = (_Float16)g3[(size_t)k*128 + n*16 + col];
  }
}

// ---------------------------------------------------------------------------
// W'[hop][b] = si_b (x) gw1[hop], f16, frag order; 32 frags (k<128 only;
// the nw rank-1 term is done in VALU in the main kernel -- R13: evicting the
// mostly-zero nw K-block cuts W' LDS 40->32KB and 8 ds_read_b128/pair).
// ---------------------------------------------------------------------------
__global__ __launch_bounds__(256) void prep_wprime_kernel(
    const _Float16* __restrict__ gw1f,
    const float* __restrict__ sum_it, _Float16* __restrict__ wg)
{
  __shared__ float si[128];
  const int b = blockIdx.x, hop = blockIdx.y, tid = threadIdx.x;
  if (tid < 128) si[tid] = sum_it[b*D_ + tid];
  __syncthreads();
  _Float16* wb = wg + ((size_t)(hop*128 + b)*32)*512;

  for (int i = 0; i < 8; ++i){
    int slot = i*256 + tid;            // 2048 = 32 frags x 64 lanes
    int f = slot >> 6, l = slot & 63;
    int g4 = (l >> 4) & 3;
    int t = f >> 3;
    const _Float16* gf = gw1f + (size_t)hop*16384 + ((size_t)f*64 + l)*8;
    int k0 = t*32 + g4*8;
    union { _Float16 h[8]; uint4 q; } o;
    #pragma unroll
    for (int j = 0; j < 8; ++j)
      o.h[j] = (_Float16)(si[k0+j] * (float)gf[j]);
    *(uint4*)(wb + (size_t)slot*8) = o.q;
  }
}

// ---------------------------------------------------------------------------
// GlobalAggregator v11 = v10 with nw K-block back in VALU and 3 blocks/CU.
// R12 pipe audit: DS was the co-dominant pipe (W' 40 ds_read_b128/pair =
// 156Kcy/CU) and LDS 62KB capped residency at 2 blocks/CU (8 waves).
// Changes: (1) nw rank-1 in VALU (~35cy) replaces 8 MFMA + 8 ds_read_b128;
// (2) LDS 53.9KB = 32K W' + 12.7K stash + 8.4K catl -> 3 blocks/CU,
// 12 waves/CU. Single-pair loop (R5/R9: interleave spills). Stage D coop.
// ---------------------------------------------------------------------------
template<bool USE_IDS, bool OUTF32>
__global__ __launch_bounds__(256, 2) void gagg11_kernel(
    const _Float16* __restrict__ embh,
    const int* sv_ids0, const _Float16* sv_vals0,
    const int* nv_ids0, const _Float16* nv_vals0,
    const float* nw0, void* outp0, int M0, int nbpb0, int nblk0,
    const int* sv_ids1, const _Float16* sv_vals1,
    const int* nv_ids1, const _Float16* nv_vals1,
    const float* nw1, void* outp1, int M1, int nbpb1,
    const _Float16* __restrict__ wg,  const float* __restrict__ gw1_last,
    const float* __restrict__ gw2, const _Float16* __restrict__ gw3f)
{
  __shared__ _Float16 wlds[32*512];           // 32768 B: W'_b frag image
  __shared__ _Float16 stash[4][12][132];      // 12672 B (wave-private)
  __shared__ _Float16 catl[16][264];          //  8448 B (block-shared)
  const int tid  = threadIdx.x;
  const int wid  = tid >> 6;
  const int lane = tid & 63;
  const int g4   = lane >> 4;
  const int col  = lane & 15;
  const bool colv = col < S_;
  const int sc_  = colv ? col : 0;

  const bool c1 = ((int)blockIdx.x >= nblk0);
  const int  blk = c1 ? (int)blockIdx.x - nblk0 : (int)blockIdx.x;
  const int*       sv_ids  = c1 ? sv_ids1  : sv_ids0;
  const _Float16*  sv_vals = c1 ? sv_vals1 : sv_vals0;
  const int*       nv_ids  = c1 ? nv_ids1  : nv_ids0;
  const _Float16*  nv_vals = c1 ? nv_vals1 : nv_vals0;
  const float*     nw      = c1 ? nw1      : nw0;
  void*            outp    = c1 ? outp1    : outp0;
  const int        M       = c1 ? M1       : M0;
  const int        nbpb    = c1 ? nbpb1    : nbpb0;

  const int b = blk / nbpb;
  const int j = blk - b*nbpb;

  // ---- cooperative W' load: 32768B = 2048 uint4, 8 per thread -----------
  {
    const uint4* src = (const uint4*)(wg + (size_t)b*32*512);
    uint4* dst = (uint4*)wlds;
    #pragma unroll
    for (int i = 0; i < 8; ++i)
      dst[i*256 + tid] = src[i*256 + tid];
  }
  __syncthreads();

  float g2v[8], glv[8];
  #pragma unroll
  for (int n = 0; n < 8; ++n){
    g2v[n] = gw2[n*16 + col];
    glv[n] = gw1_last[n*16 + col];
  }

  for (int np = 0; np < 4; ++np){
    const int li0 = j*16 + wid*4 + np;
    const int li  = li0 < M ? li0 : M-1;
    const int p   = b*M + li;

    const _Float16* nvrow = USE_IDS
        ? embh + (size_t)nv_ids[p*S_ + sc_]*D_
        : nv_vals + ((size_t)p*S_ + sc_)*D_;

    f32x4 acc[8];
    #pragma unroll
    for (int n = 0; n < 8; ++n) acc[n] = (f32x4){0.f,0.f,0.f,0.f};

    #pragma unroll
    for (int t = 0; t < 4; ++t){
      half8 af = {0,0,0,0,0,0,0,0};
      if (colv){
        af = *(const half8*)(nvrow + t*32 + g4*8);
        union { half8 v; uint2 q[2]; } ua;
        ua.v = af;
        _Float16* sp = &stash[wid][col][t*32 + g4*8];
        *(uint2*)sp       = ua.q[0];
        *(uint2*)(sp + 4) = ua.q[1];
      }
      #pragma unroll
      for (int n = 0; n < 8; ++n){
        half8 wf = *(const half8*)(wlds + ((size_t)(t*8+n)*64 + lane)*8);
        acc[n] = __builtin_amdgcn_mfma_f32_16x16x32_f16(af, wf, acc[n], 0, 0, 0);
      }
    }

    // -------- nw rank-1 (VALU) + scores -> softmax -> stage C -> catl -----
    float nwv[4];
    #pragma unroll
    for (int r = 0; r < 4; ++r){
      int s = g4*4 + r;
      nwv[r] = nw[p*S_ + (s < S_ ? s : 0)];
    }
    float sc4[4];
    #pragma unroll
    for (int r = 0; r < 4; ++r){
      float pr = 0.f;
      #pragma unroll
      for (int n = 0; n < 8; ++n){
        float tv = acc[n][r] + nwv[r]*glv[n];
        pr = fmaf(lrelu(tv), g2v[n], pr);
      }
      pr += __shfl_xor(pr, 1); pr += __shfl_xor(pr, 2);
      pr += __shfl_xor(pr, 4); pr += __shfl_xor(pr, 8);
      sc4[r] = pr;
    }
    float w[S_];
    {
      float ss[S_];
      #pragma unroll
      for (int grp = 0; grp < 3; ++grp)
        #pragma unroll
        for (int r = 0; r < 4; ++r)
          ss[grp*4 + r] = __shfl(sc4[r], grp*16);
      float m01 = fmaxf(ss[0], ss[1]),  m23 = fmaxf(ss[2], ss[3]);
      float m45 = fmaxf(ss[4], ss[5]),  m67 = fmaxf(ss[6], ss[7]);
      float m89 = fmaxf(ss[8], ss[9]),  mab = fmaxf(ss[10], ss[11]);
      float m = fmaxf(fmaxf(fmaxf(m01, m23), fmaxf(m45, m67)), fmaxf(m89, mab));
      float sum = 0.f;
      #pragma unroll
      for (int s = 0; s < S_; ++s){ ss[s] = fexp(ss[s]-m); sum += ss[s]; }
      float inv = frcp(sum);
      #pragma unroll
      for (int s = 0; s < S_; ++s) w[s] = ss[s]*inv;
    }
    float aggx = 0.f, aggy = 0.f;
    #pragma unroll
    for (int s = 0; s < S_; ++s){
      union { unsigned q; _Float16 h[2]; } v;
      v.q = *(const unsigned*)&stash[wid][s][2*lane];
      aggx = fmaf(w[s], (float)v.h[0], aggx);
      aggy = fmaf(w[s], (float)v.h[1], aggy);
    }
    const _Float16* svrow = USE_IDS ? embh + (size_t)sv_ids[p]*D_
                                    : sv_vals + (size_t)p*D_;
    const int row = wid*4 + np;
    *(unsigned*)&catl[row][2*lane] = *(const unsigned*)(svrow + 2*lane);
    union { unsigned q; _Float16 h[2]; } pk;
    pk.h[0] = (_Float16)aggx; pk.h[1] = (_Float16)aggy;
    *(unsigned*)&catl[row][D_ + 2*lane] = pk.q;
  }

  __syncthreads();   // catl is block-shared

  // -------- stage D: [16x256]@[256x128] f16 MFMA, wave owns 2 n-frags -----
  const half8* g3fp = (const half8*)gw3f;
  f32x4 dacc[2];
  dacc[0] = (f32x4){0.f,0.f,0.f,0.f};
  dacc[1] = (f32x4){0.f,0.f,0.f,0.f};

  #pragma unroll
  for (int kt = 0; kt < 8; ++kt){
    half8 afr = *(const half8*)&catl[col][kt*32 + g4*8];
    #pragma unroll
    for (int nn = 0; nn < 2; ++nn){
      int n = wid*2 + nn;
      dacc[nn] = __builtin_amdgcn_mfma_f32_16x16x32_f16(afr, g3fp[(kt*8+n)*64 + lane], dacc[nn], 0, 0, 0);
    }
  }

  #pragma unroll
  for (int nn = 0; nn < 2; ++nn){
    int n = wid*2 + nn;
    #pragma unroll
    for (int r = 0; r < 4; ++r){
      int li = j*16 + g4*4 + r;
      if (li < M){
        size_t off = (size_t)(b*M + li)*D_ + n*16 + col;
        float v = fmaxf(dacc[nn][r], 0.f);
        if (OUTF32) ((float*)outp)[off] = v;
        else        ((_Float16*)outp)[off] = (_Float16)v;
      }
    }
  }
}

// ---------------------------------------------------------------------------
// output = h_local + s_global
// ---------------------------------------------------------------------------
__global__ void final_add_kernel(float* __restrict__ dout){
  int i = blockIdx.x*blockDim.x + threadIdx.x;
  const int n4 = (B_*L_*D_)/4;
  if (i < n4){
    float4* o = (float4*)dout;
    const float4* s = (const float4*)(dout + B_*L_*D_);
    float4 a = o[i], b = s[i];
    a.x += b.x; a.y += b.y; a.z += b.z; a.w += b.w;
    o[i] = a;
  }
}

extern "C" void kernel_launch(void* const* d_in, const int* in_sizes, int n_in,
                              void* d_out, int out_size, void* d_ws, size_t ws_size,
                              hipStream_t stream)
{
  const int*   inputs  = (const int*)  d_in[0];
  const int*   adj     = (const int*)  d_in[1];
  const int*   mask    = (const int*)  d_in[2];
  const int*   item    = (const int*)  d_in[3];
  const float* emb     = (const float*)d_in[4];
  const int*   adj_all = (const int*)  d_in[5];
  const float* num_w   = (const float*)d_in[6];
  const float* a0      = (const float*)d_in[7];
  const float* a1      = (const float*)d_in[8];
  const float* a2      = (const float*)d_in[9];
  const float* a3      = (const float*)d_in[10];
  const float* gw1     = (const float*)d_in[11];  // [2][129][128]
  const float* gw2     = (const float*)d_in[12];  // [2][128]
  const float* gw3     = (const float*)d_in[13];  // [2][256][128]

  float* out     = (float*)d_out;
  float* hlocal  = out;
  float* sglobal = out + B_*L_*D_;

  char* ws = (char*)d_ws;
  size_t off = 0;
  auto alloc = [&](size_t bytes)->char*{
    char* pp = ws + off; off += (bytes + 255) & ~(size_t)255; return pp;
  };
  float*    sum_it = (float*)alloc((size_t)B_*D_*sizeof(float));
  int*      n1     = (int*)  alloc((size_t)B_*L_*S_*sizeof(int));
  float*    w0     = (float*)alloc((size_t)B_*L_*S_*sizeof(float));
  int*      n2     = (int*)  alloc((size_t)B_*L_*S_*S_*sizeof(int));
  float*    w1     = (float*)alloc((size_t)B_*L_*S_*S_*sizeof(float));
  _Float16* out0h  = (_Float16*)alloc((size_t)B_*L_*D_*sizeof(_Float16));
  _Float16* out1h  = (_Float16*)alloc((size_t)B_*L_*S_*D_*sizeof(_Float16));
  _Float16* embh   = (_Float16*)alloc((size_t)100000*D_*sizeof(_Float16));
  _Float16* gw1f   = (_Float16*)alloc((size_t)2*16384*sizeof(_Float16));
  _Float16* gw3f   = (_Float16*)alloc((size_t)2*32768*sizeof(_Float16));
  _Float16* wgAll  = (_Float16*)alloc((size_t)2*128*32*512*sizeof(_Float16)); // 8.4MB

  emb2f16_kernel<<<(100000*D_/4 + 255)/256, 256, 0, stream>>>(emb, embh, 100000*D_/4);
  prep_gw1frag_kernel<<<dim3(8,2), 256, 0, stream>>>(gw1, gw1f);
  prep_gw3frag_kernel<<<dim3(16,2), 256, 0, stream>>>(gw3, gw3f);
  local_agg_kernel<<<dim3(B_,4), 256, 0, stream>>>(inputs, adj, emb, a0, a1, a2, a3, hlocal);
  sum_item_kernel<<<B_, 128, 0, stream>>>(item, mask, emb, sum_it);
  build_nbr_kernel<<<(B_*L_*S_ + 255)/256, 256, 0, stream>>>(inputs, B_*L_*S_, adj_all, num_w, n1, w0);
  build_nbr_kernel<<<(B_*L_*S_*S_ + 255)/256, 256, 0, stream>>>(n1, B_*L_*S_*S_, adj_all, num_w, n2, w1);
  prep_wprime_kernel<<<dim3(B_,2), 256, 0, stream>>>(gw1f, sum_it, wgAll);

  // Fused hop0: cfg0 = pass A (ids, emb -> out0h, M=50, nbpb=4, 512 blocks)
  //             cfg1 = pass B (ids, emb -> out1h, M=600, nbpb=38, 4864 blocks)
  {
    const int nblkA = B_*4;        // 512
    const int nblkB = B_*38;       // 4864
    gagg11_kernel<true,false><<<nblkA + nblkB, 256, 0, stream>>>(
        embh,
        inputs, nullptr, n1, nullptr, w0, out0h, L_,   4, nblkA,
        n1,     nullptr, n2, nullptr, w1, out1h, L_*S_, 38,
        wgAll, gw1 + 128*128, gw2, gw3f);
  }
  // hop1 (pass C): vals = out0h/out1h, hop1 W', f32 out -> sglobal
  {
    const int nblkC = B_*4;        // 512
    gagg11_kernel<false,true><<<nblkC, 256, 0, stream>>>(
        embh,
        nullptr, out0h, nullptr, out1h, w0, sglobal, L_, 4, nblkC,
        nullptr, out0h, nullptr, out1h, w0, sglobal, L_, 4,
        wgAll + (size_t)128*32*512, gw1 + 129*128 + 128*128, gw2 + 128, gw3f + 32768);
  }

  final_add_kernel<<<((B_*L_*D_/4) + 255)/256, 256, 0, stream>>>(out);
}

// Round 14
// 190.751 us; speedup vs baseline: 2.3803x; 1.2333x over previous
//
#include <hip/hip_runtime.h>
#include <hip/hip_bf16.h>
#include <math.h>

#define B_ 128
#define L_ 50
#define D_ 128
#define S_ 12
#define NEG_INF_ -9e15f

typedef __attribute__((ext_vector_type(8))) _Float16 half8;
typedef __attribute__((ext_vector_type(4))) float f32x4;

static __device__ __forceinline__ float lrelu(float x){ return fmaxf(x, 0.2f*x); }
static __device__ __forceinline__ float fexp(float x){ return __expf(x); }
static __device__ __forceinline__ float frcp(float x){ return __builtin_amdgcn_rcpf(x); }

// ---------------------------------------------------------------------------
// Local aggregator: 4-edge-type GAT. Grid (B, 4).
// ---------------------------------------------------------------------------
__global__ __launch_bounds__(256) void local_agg_kernel(
    const int* __restrict__ inputs, const int* __restrict__ adj,
    const float* __restrict__ emb,
    const float* __restrict__ a0, const float* __restrict__ a1,
    const float* __restrict__ a2, const float* __restrict__ a3,
    float* __restrict__ hlocal_out)
{
  __shared__ float hs[L_][129];
  __shared__ float alds[4][129];
  __shared__ float att[13][51];
  const int b = blockIdx.x, tid = threadIdx.x;
  const int r0 = blockIdx.y * 13;
  const int nr = (L_ - r0) < 13 ? (L_ - r0) : 13;

  if (tid < 128){
    alds[0][tid] = a0[tid]; alds[1][tid] = a1[tid];
    alds[2][tid] = a2[tid]; alds[3][tid] = a3[tid];
  }
  for (int i = tid; i < L_*D_; i += 256){
    int r = i >> 7, d = i & 127;
    hs[r][d] = emb[(size_t)inputs[b*L_ + r]*D_ + d];
  }
  __syncthreads();

  for (int pth = tid; pth < nr*L_; pth += 256){
    int i = pth / L_, j = pth % L_;
    int at = adj[b*L_*L_ + (r0+i)*L_ + j];
    float lg = NEG_INF_;
    if (at >= 1 && at <= 4){
      const float* av = alds[at-1];
      float acc = 0.f;
      #pragma unroll 4
      for (int d = 0; d < D_; ++d) acc = fmaf(hs[r0+i][d]*hs[j][d], av[d], acc);
      lg = lrelu(acc);
    }
    att[i][j] = lg;
  }
  __syncthreads();

  if (tid < nr){
    float m = -1e30f;
    for (int j = 0; j < L_; ++j) m = fmaxf(m, att[tid][j]);
    float sum = 0.f;
    for (int j = 0; j < L_; ++j){ float e = fexp(att[tid][j]-m); att[tid][j] = e; sum += e; }
    float inv = frcp(sum);
    for (int j = 0; j < L_; ++j) att[tid][j] *= inv;
  }
  __syncthreads();

  for (int i2 = tid; i2 < nr*D_; i2 += 256){
    int r = i2 >> 7, d = i2 & 127;
    float acc = 0.f;
    #pragma unroll 5
    for (int j = 0; j < L_; ++j) acc = fmaf(att[r][j], hs[j][d], acc);
    hlocal_out[(size_t)b*L_*D_ + (size_t)(r0+r)*D_ + d] = acc;
  }
}

// ---------------------------------------------------------------------------
// Merged neighbor expansion: one kernel computes n1/w0 AND n2/w1 via a
// 2-level gather chain (saves a launch + the n1 round-trip dependency).
// ---------------------------------------------------------------------------
__global__ void build_nbr2_kernel(const int* __restrict__ inputs,
                                  const int* __restrict__ adj_all,
                                  const float* __restrict__ num_w,
                                  int* __restrict__ n1, float* __restrict__ w0,
                                  int* __restrict__ n2, float* __restrict__ w1)
{
  int t = blockIdx.x*256 + threadIdx.x;          // 0..921599
  if (t >= B_*L_*S_*S_) return;
  int i1 = t / S_;                               // 0..76799
  int s2 = t - i1*S_;
  int i0 = i1 / S_;                              // 0..6399
  int s1 = i1 - i0*S_;
  int parent0 = inputs[i0];
  int parent1 = adj_all[(size_t)parent0*S_ + s1];
  n2[t] = adj_all[(size_t)parent1*S_ + s2];
  w1[t] = num_w[(size_t)parent1*S_ + s2];
  if (s2 == 0){
    n1[i1] = parent1;
    w0[i1] = num_w[(size_t)parent0*S_ + s1];
  }
}

// ---------------------------------------------------------------------------
// Fused prep: emb f32->f16 (12500 blocks) + gw1 frags (16) + gw3 frags (32).
// Frag order (16x16x32): frag f: lane l, slot j <- W[k0+(l>>4)*8+j][n*16+(l&15)]
// ---------------------------------------------------------------------------
__global__ void prep_all_kernel(const float* __restrict__ emb, _Float16* __restrict__ embh,
                                const float* __restrict__ gw1, _Float16* __restrict__ gw1f,
                                const float* __restrict__ gw3, _Float16* __restrict__ gw3f)
{
  const int blk = blockIdx.x, tid = threadIdx.x;
  if (blk < 12500){
    int i = blk*256 + tid;                       // < 3,200,000 exactly
    float4 v = ((const float4*)emb)[i];
    union { _Float16 h[4]; uint2 u; } pk;
    pk.h[0] = (_Float16)v.x; pk.h[1] = (_Float16)v.y;
    pk.h[2] = (_Float16)v.z; pk.h[3] = (_Float16)v.w;
    ((uint2*)embh)[i] = pk.u;
  } else if (blk < 12516){
    int rel = blk - 12500;                       // 0..15
    int hop = rel >> 3, bx = rel & 7;
    int idx = bx*256 + tid;                      // 0..2047
    int lane = idx & 63, f = idx >> 6;
    int t = f >> 3, n = f & 7;
    int g4 = lane >> 4, col = lane & 15;
    const float* g1 = gw1 + (size_t)hop*129*128;
    size_t base = (size_t)hop*16384 + ((size_t)f*64 + lane)*8;
    #pragma unroll
    for (int j = 0; j < 8; ++j){
      int k = t*32 + g4*8 + j;
      gw1f[base + j] = (_Float16)g1[(size_t)k*128 + n*16 + col];
    }
  } else {
    int rel = blk - 12516;                       // 0..31
    int hop = rel >> 4, bx = rel & 15;
    int idx = bx*256 + tid;                      // 0..4095
    int lane = idx & 63, n = (idx >> 6) & 7, kt = idx >> 9;
    int g4 = lane >> 4, col = lane & 15;
    const float* g3 = gw3 + (size_t)hop*256*128;
    size_t base = (size_t)hop*32768 + ((size_t)(kt*8 + n)*64 + lane)*8;
    #pragma unroll
    for (int j = 0; j < 8; ++j){
      int k = kt*32 + g4*8 + j;
      gw3f[base + j] = (_Float16)g3[(size_t)k*128 + n*16 + col];
    }
  }
}

// ---------------------------------------------------------------------------
// W'[hop][b] = si_b (x) gw1[hop], f16, frag order; 32 frags (k<128; nw rank-1
// stays in VALU in gagg). Session-mean si computed IN-BLOCK (sum_item fused).
// ---------------------------------------------------------------------------
__global__ __launch_bounds__(256) void prep_wprime_kernel(
    const _Float16* __restrict__ gw1f,
    const int* __restrict__ item, const int* __restrict__ mask,
    const float* __restrict__ emb, _Float16* __restrict__ wg)
{
  __shared__ float si[128];
  const int b = blockIdx.x, hop = blockIdx.y, tid = threadIdx.x;
  if (tid < 128){
    float acc = 0.f, cnt = 0.f;
    for (int l = 0; l < L_; ++l){
      float mf = (float)mask[b*L_ + l];
      acc = fmaf(mf, emb[(size_t)item[b*L_+l]*D_ + tid], acc);
      cnt += mf;
    }
    si[tid] = acc / cnt;
  }
  __syncthreads();
  _Float16* wb = wg + ((size_t)(hop*128 + b)*32)*512;

  for (int i = 0; i < 8; ++i){
    int slot = i*256 + tid;            // 2048 = 32 frags x 64 lanes
    int f = slot >> 6, l = slot & 63;
    int g4 = (l >> 4) & 3;
    int t = f >> 3;
    const _Float16* gf = gw1f + (size_t)hop*16384 + ((size_t)f*64 + l)*8;
    int k0 = t*32 + g4*8;
    union { _Float16 h[8]; uint4 q; } o;
    #pragma unroll
    for (int j = 0; j < 8; ++j)
      o.h[j] = (_Float16)(si[k0+j] * (float)gf[j]);
    *(uint4*)(wb + (size_t)slot*8) = o.q;
  }
}

// ---------------------------------------------------------------------------
// GlobalAggregator v12 = v11 + software-pipelined gathers.
// R13 lesson: occupancy is REG-capped at 2 waves/SIMD (116 arch + ~40 acc);
// LDS never was the cap; and anything <=~230 regs is FREE. So spend ~32 regs
// on a 2-level prefetch rotation: nv_ids 2 pairs ahead, A-frag row loads
// (pf[4]) 1 pair ahead -> the ~500cy L3 gather latency hides under the
// previous pair's compute. nw/sv loads hoisted to iteration start.
// Single-pair acc (R5/R9: dual-acc interleave spills). Stage D block-coop.
// OUTF32 path also folds final_add: hout[off] = h_local + v.
// ---------------------------------------------------------------------------
template<bool USE_IDS, bool OUTF32>
__global__ __launch_bounds__(256, 2) void gagg12_kernel(
    const _Float16* __restrict__ embh,
    const int* sv_ids0, const _Float16* sv_vals0,
    const int* nv_ids0, const _Float16* nv_vals0,
    const float* nw0, void* outp0, int M0, int nbpb0, int nblk0,
    const int* sv_ids1, const _Float16* sv_vals1,
    const int* nv_ids1, const _Float16* nv_vals1,
    const float* nw1, void* outp1, int M1, int nbpb1,
    const _Float16* __restrict__ wg,  const float* __restrict__ gw1_last,
    const float* __restrict__ gw2, const _Float16* __restrict__ gw3f,
    float* __restrict__ hout)
{
  __shared__ _Float16 wlds[32*512];           // 32768 B: W'_b frag image
  __shared__ _Float16 stash[4][12][132];      // 12672 B (wave-private)
  __shared__ _Float16 catl[16][264];          //  8448 B (block-shared)
  const int tid  = threadIdx.x;
  const int wid  = tid >> 6;
  const int lane = tid & 63;
  const int g4   = lane >> 4;
  const int col  = lane & 15;
  const bool colv = col < S_;
  const int sc_  = colv ? col : 0;

  const bool c1 = ((int)blockIdx.x >= nblk0);
  const int  blk = c1 ? (int)blockIdx.x - nblk0 : (int)blockIdx.x;
  const int*       sv_ids  = c1 ? sv_ids1  : sv_ids0;
  const _Float16*  sv_vals = c1 ? sv_vals1 : sv_vals0;
  const int*       nv_ids  = c1 ? nv_ids1  : nv_ids0;
  const _Float16*  nv_vals = c1 ? nv_vals1 : nv_vals0;
  const float*     nw      = c1 ? nw1      : nw0;
  void*            outp    = c1 ? outp1    : outp0;
  const int        M       = c1 ? M1       : M0;
  const int        nbpb    = c1 ? nbpb1    : nbpb0;

  const int b = blk / nbpb;
  const int j = blk - b*nbpb;

  // ---- cooperative W' load: 32768B = 2048 uint4, 8 per thread -----------
  {
    const uint4* src = (const uint4*)(wg + (size_t)b*32*512);
    uint4* dst = (uint4*)wlds;
    #pragma unroll
    for (int i = 0; i < 8; ++i)
      dst[i*256 + tid] = src[i*256 + tid];
  }
  __syncthreads();

  float g2v[8], glv[8];
  #pragma unroll
  for (int n = 0; n < 8; ++n){
    g2v[n] = gw2[n*16 + col];
    glv[n] = gw1_last[n*16 + col];
  }

  auto pidx = [&](int np_)->int{
    int li0 = j*16 + wid*4 + np_;
    int li  = li0 < M ? li0 : M-1;
    return b*M + li;
  };

  // ---- prefetch pipeline: ids 2 ahead, A-frag rows 1 ahead ---------------
  const half8 z8 = {0,0,0,0,0,0,0,0};
  half8 pf[4];
  int idn = 0;
  {
    const int p0_ = pidx(0);
    const _Float16* r0 = USE_IDS ? embh + (size_t)nv_ids[p0_*S_ + sc_]*D_
                                 : nv_vals + ((size_t)p0_*S_ + sc_)*D_;
    #pragma unroll
    for (int t = 0; t < 4; ++t)
      pf[t] = colv ? *(const half8*)(r0 + t*32 + g4*8) : z8;
    if (USE_IDS) idn = nv_ids[pidx(1)*S_ + sc_];
  }

  for (int np = 0; np < 4; ++np){
    const int p = pidx(np);

    // current pair's frags (wait lands here; loads had a full iteration)
    half8 af[4];
    #pragma unroll
    for (int t = 0; t < 4; ++t) af[t] = colv ? pf[t] : z8;

    // issue NEXT pair's row loads + id 2 ahead
    if (np < 3){
      const _Float16* rn = USE_IDS ? embh + (size_t)idn*D_
                                   : nv_vals + ((size_t)pidx(np+1)*S_ + sc_)*D_;
      #pragma unroll
      for (int t = 0; t < 4; ++t)
        pf[t] = colv ? *(const half8*)(rn + t*32 + g4*8) : z8;
      if (USE_IDS && np < 2) idn = nv_ids[pidx(np+2)*S_ + sc_];
    }

    // hoist independent loads: nw + sv row
    float nwv[4];
    #pragma unroll
    for (int r = 0; r < 4; ++r){
      int s = g4*4 + r;
      nwv[r] = nw[p*S_ + (s < S_ ? s : 0)];
    }
    const _Float16* svrow = USE_IDS ? embh + (size_t)sv_ids[p]*D_
                                    : sv_vals + (size_t)p*D_;
    unsigned sv2q = *(const unsigned*)(svrow + 2*lane);

    // stash writes + MFMA
    #pragma unroll
    for (int t = 0; t < 4; ++t){
      if (colv){
        union { half8 v; uint2 q[2]; } ua;
        ua.v = af[t];
        _Float16* sp = &stash[wid][col][t*32 + g4*8];
        *(uint2*)sp       = ua.q[0];
        *(uint2*)(sp + 4) = ua.q[1];
      }
    }
    f32x4 acc[8];
    #pragma unroll
    for (int n = 0; n < 8; ++n) acc[n] = (f32x4){0.f,0.f,0.f,0.f};
    #pragma unroll
    for (int t = 0; t < 4; ++t){
      #pragma unroll
      for (int n = 0; n < 8; ++n){
        half8 wf = *(const half8*)(wlds + ((size_t)(t*8+n)*64 + lane)*8);
        acc[n] = __builtin_amdgcn_mfma_f32_16x16x32_f16(af[t], wf, acc[n], 0, 0, 0);
      }
    }

    // -------- nw rank-1 (VALU) + scores -> softmax -> stage C -> catl -----
    float sc4[4];
    #pragma unroll
    for (int r = 0; r < 4; ++r){
      float pr = 0.f;
      #pragma unroll
      for (int n = 0; n < 8; ++n){
        float tv = acc[n][r] + nwv[r]*glv[n];
        pr = fmaf(lrelu(tv), g2v[n], pr);
      }
      pr += __shfl_xor(pr, 1); pr += __shfl_xor(pr, 2);
      pr += __shfl_xor(pr, 4); pr += __shfl_xor(pr, 8);
      sc4[r] = pr;
    }
    float w[S_];
    {
      float ss[S_];
      #pragma unroll
      for (int grp = 0; grp < 3; ++grp)
        #pragma unroll
        for (int r = 0; r < 4; ++r)
          ss[grp*4 + r] = __shfl(sc4[r], grp*16);
      float m01 = fmaxf(ss[0], ss[1]),  m23 = fmaxf(ss[2], ss[3]);
      float m45 = fmaxf(ss[4], ss[5]),  m67 = fmaxf(ss[6], ss[7]);
      float m89 = fmaxf(ss[8], ss[9]),  mab = fmaxf(ss[10], ss[11]);
      float m = fmaxf(fmaxf(fmaxf(m01, m23), fmaxf(m45, m67)), fmaxf(m89, mab));
      float sum = 0.f;
      #pragma unroll
      for (int s = 0; s < S_; ++s){ ss[s] = fexp(ss[s]-m); sum += ss[s]; }
      float inv = frcp(sum);
      #pragma unroll
      for (int s = 0; s < S_; ++s) w[s] = ss[s]*inv;
    }
    float aggx = 0.f, aggy = 0.f;
    #pragma unroll
    for (int s = 0; s < S_; ++s){
      union { unsigned q; _Float16 h[2]; } v;
      v.q = *(const unsigned*)&stash[wid][s][2*lane];
      aggx = fmaf(w[s], (float)v.h[0], aggx);
      aggy = fmaf(w[s], (float)v.h[1], aggy);
    }
    const int row = wid*4 + np;
    *(unsigned*)&catl[row][2*lane] = sv2q;
    union { unsigned q; _Float16 h[2]; } pk;
    pk.h[0] = (_Float16)aggx; pk.h[1] = (_Float16)aggy;
    *(unsigned*)&catl[row][D_ + 2*lane] = pk.q;
  }

  __syncthreads();   // catl is block-shared

  // -------- stage D: [16x256]@[256x128] f16 MFMA, wave owns 2 n-frags -----
  const half8* g3fp = (const half8*)gw3f;
  f32x4 dacc[2];
  dacc[0] = (f32x4){0.f,0.f,0.f,0.f};
  dacc[1] = (f32x4){0.f,0.f,0.f,0.f};

  #pragma unroll
  for (int kt = 0; kt < 8; ++kt){
    half8 afr = *(const half8*)&catl[col][kt*32 + g4*8];
    #pragma unroll
    for (int nn = 0; nn < 2; ++nn){
      int n = wid*2 + nn;
      dacc[nn] = __builtin_amdgcn_mfma_f32_16x16x32_f16(afr, g3fp[(kt*8+n)*64 + lane], dacc[nn], 0, 0, 0);
    }
  }

  #pragma unroll
  for (int nn = 0; nn < 2; ++nn){
    int n = wid*2 + nn;
    #pragma unroll
    for (int r = 0; r < 4; ++r){
      int li = j*16 + g4*4 + r;
      if (li < M){
        size_t off = (size_t)(b*M + li)*D_ + n*16 + col;
        float v = fmaxf(dacc[nn][r], 0.f);
        if (OUTF32){
          ((float*)outp)[off] = v;          // s_global region
          hout[off] += v;                   // output = h_local + s_global
        } else {
          ((_Float16*)outp)[off] = (_Float16)v;
        }
      }
    }
  }
}

extern "C" void kernel_launch(void* const* d_in, const int* in_sizes, int n_in,
                              void* d_out, int out_size, void* d_ws, size_t ws_size,
                              hipStream_t stream)
{
  const int*   inputs  = (const int*)  d_in[0];
  const int*   adj     = (const int*)  d_in[1];
  const int*   mask    = (const int*)  d_in[2];
  const int*   item    = (const int*)  d_in[3];
  const float* emb     = (const float*)d_in[4];
  const int*   adj_all = (const int*)  d_in[5];
  const float* num_w   = (const float*)d_in[6];
  const float* a0      = (const float*)d_in[7];
  const float* a1      = (const float*)d_in[8];
  const float* a2      = (const float*)d_in[9];
  const float* a3      = (const float*)d_in[10];
  const float* gw1     = (const float*)d_in[11];  // [2][129][128]
  const float* gw2     = (const float*)d_in[12];  // [2][128]
  const float* gw3     = (const float*)d_in[13];  // [2][256][128]

  float* out     = (float*)d_out;
  float* hlocal  = out;
  float* sglobal = out + B_*L_*D_;

  char* ws = (char*)d_ws;
  size_t off = 0;
  auto alloc = [&](size_t bytes)->char*{
    char* pp = ws + off; off += (bytes + 255) & ~(size_t)255; return pp;
  };
  int*      n1     = (int*)  alloc((size_t)B_*L_*S_*sizeof(int));
  float*    w0     = (float*)alloc((size_t)B_*L_*S_*sizeof(float));
  int*      n2     = (int*)  alloc((size_t)B_*L_*S_*S_*sizeof(int));
  float*    w1     = (float*)alloc((size_t)B_*L_*S_*S_*sizeof(float));
  _Float16* out0h  = (_Float16*)alloc((size_t)B_*L_*D_*sizeof(_Float16));
  _Float16* out1h  = (_Float16*)alloc((size_t)B_*L_*S_*D_*sizeof(_Float16));
  _Float16* embh   = (_Float16*)alloc((size_t)100000*D_*sizeof(_Float16));
  _Float16* gw1f   = (_Float16*)alloc((size_t)2*16384*sizeof(_Float16));
  _Float16* gw3f   = (_Float16*)alloc((size_t)2*32768*sizeof(_Float16));
  _Float16* wgAll  = (_Float16*)alloc((size_t)2*128*32*512*sizeof(_Float16)); // 8.4MB

  // 1) fused prep: emb->f16 + gw1/gw3 frag packs
  prep_all_kernel<<<12548, 256, 0, stream>>>(emb, embh, gw1, gw1f, gw3, gw3f);
  // 2) local GAT (independent)
  local_agg_kernel<<<dim3(B_,4), 256, 0, stream>>>(inputs, adj, emb, a0, a1, a2, a3, hlocal);
  // 3) merged 2-hop neighbor expansion
  build_nbr2_kernel<<<(B_*L_*S_*S_ + 255)/256, 256, 0, stream>>>(
      inputs, adj_all, num_w, n1, w0, n2, w1);
  // 4) W' (session-mean fused in-block)
  prep_wprime_kernel<<<dim3(B_,2), 256, 0, stream>>>(gw1f, item, mask, emb, wgAll);

  // 5) Fused hop0: cfg0 = pass A (ids -> out0h, M=50), cfg1 = pass B (-> out1h, M=600)
  {
    const int nblkA = B_*4;        // 512
    const int nblkB = B_*38;       // 4864
    gagg12_kernel<true,false><<<nblkA + nblkB, 256, 0, stream>>>(
        embh,
        inputs, nullptr, n1, nullptr, w0, out0h, L_,   4, nblkA,
        n1,     nullptr, n2, nullptr, w1, out1h, L_*S_, 38,
        wgAll, gw1 + 128*128, gw2, gw3f, nullptr);
  }
  // 6) hop1 (pass C): vals = out0h/out1h, hop1 W'; writes sglobal AND
  //    folds the final add: out = h_local + s_global.
  {
    const int nblkC = B_*4;        // 512
    gagg12_kernel<false,true><<<nblkC, 256, 0, stream>>>(
        embh,
        nullptr, out0h, nullptr, out1h, w0, sglobal, L_, 4, nblkC,
        nullptr, out0h, nullptr, out1h, w0, sglobal, L_, 4,
        wgAll + (size_t)128*32*512, gw1 + 129*128 + 128*128, gw2 + 128, gw3f + 32768,
        hlocal);
  }
}